// Round 2
// baseline (45741.125 us; speedup 1.0000x reference)
//
#include <hip/hip_runtime.h>
#include <math.h>

#define DIVUP(a,b) (((a)+(b)-1)/(b))

namespace {

constexpr int B=8, T=12, N=883, CIN=3, C=64, E=10, H=8, HD=8, TOPK=48, L=8;
constexpr int SKC=256, F7=7, T13=13;

__device__ __forceinline__ float geluf(float x){ return 0.5f*x*(1.0f+erff(x*0.7071067811865475f)); }
__device__ __forceinline__ float sigmf(float x){ return 1.0f/(1.0f+expf(-x)); }

// ---------------- graph generation ----------------
__global__ void k_dft(const float* __restrict__ x, float* __restrict__ xf){
  int idx = blockIdx.x*256 + threadIdx.x;
  if(idx >= B*F7*N) return;
  int n = idx % N; int f = (idx/N) % F7; int b = idx/(N*F7);
  float re=0.f, im=0.f;
  for(int t=0;t<T;t++){
    float v = x[((size_t)(b*T+t)*N+n)*CIN];
    float ang = -6.283185307179586f * (float)(f*t) / 12.0f;
    re += v*cosf(ang); im += v*sinf(ang);
  }
  xf[idx] = sqrtf(re*re+im*im);
}

// l2 norm over freq axis, per (b,n)
__global__ void k_l2f(float* __restrict__ xf){
  int idx = blockIdx.x*256 + threadIdx.x;
  if(idx >= B*N) return;
  int n = idx % N; int b = idx / N;
  float s=0.f;
  for(int f=0;f<F7;f++){ float v=xf[((size_t)b*F7+f)*N+n]; s+=v*v; }
  float inv = 1.0f/fmaxf(sqrtf(s), 1e-12f);
  for(int f=0;f<F7;f++) xf[((size_t)b*F7+f)*N+n] *= inv;
}

// l2 norm over node axis, per (b,f)
__global__ void k_l2n(float* __restrict__ xf){
  int bf = blockIdx.x; int tid = threadIdx.x;
  __shared__ float red[256];
  size_t base = (size_t)bf*N;
  float s=0.f;
  for(int i=tid;i<N;i+=256){ float v=xf[base+i]; s+=v*v; }
  red[tid]=s; __syncthreads();
  for(int k=128;k>0;k>>=1){ if(tid<k) red[tid]+=red[tid+k]; __syncthreads(); }
  float inv = 1.0f/fmaxf(sqrtf(red[0]), 1e-12f);
  __syncthreads();
  for(int i=tid;i<N;i+=256) xf[base+i]*=inv;
}

__global__ void k_x1(const float* __restrict__ x, const float* __restrict__ xf,
                     const float* __restrict__ E3, const float* __restrict__ TiD,
                     const float* __restrict__ DiW, const float* __restrict__ Wx,
                     const float* __restrict__ Wd, float* __restrict__ x1){
  int idx = blockIdx.x*256+threadIdx.x;
  if(idx>=B*N) return;
  int n=idx%N, b=idx/N;
  float xc[40];
  for(int d=0;d<E;d++){
    float a=0.f;
    for(int f=0;f<F7;f++) a += xf[((size_t)b*F7+f)*N+n]*Wx[f*E+d];
    xc[d]=a;
  }
  for(int d=0;d<E;d++) xc[10+d]=E3[n*E+d];
  int ti = (int)(x[((size_t)(b*T+(T-1))*N+n)*CIN+1]*288.0f);
  int dw = (int)(x[((size_t)(b*T+(T-1))*N+n)*CIN+2]);
  for(int d=0;d<E;d++) xc[20+d]=TiD[ti*E+d];
  for(int d=0;d<E;d++) xc[30+d]=DiW[dw*E+d];
  for(int e=0;e<E;e++){
    float a=0.f;
    for(int f=0;f<40;f++) a += xc[f]*Wd[((size_t)n*40+f)*E+e];
    x1[(size_t)idx*E+e]=fmaxf(a,0.f);
  }
}

__global__ void k_lnstats(const float* __restrict__ x1, float* __restrict__ st){
  int b=blockIdx.x, tid=threadIdx.x;
  __shared__ float rs[256], rq[256];
  const int M=N*E;
  float s=0.f,q=0.f;
  for(int i=tid;i<M;i+=256){ float v=x1[(size_t)b*M+i]; s+=v; q+=v*v; }
  rs[tid]=s; rq[tid]=q; __syncthreads();
  for(int k=128;k>0;k>>=1){ if(tid<k){ rs[tid]+=rs[tid+k]; rq[tid]+=rq[tid+k]; } __syncthreads(); }
  if(tid==0){ float mu=rs[0]/M; float var=rq[0]/M-mu*mu; st[b*2]=mu; st[b*2+1]=var; }
}

__global__ void k_dew(const float* __restrict__ x1, const float* __restrict__ st,
                      const float* __restrict__ Wxabs, float* __restrict__ dew){
  int idx=blockIdx.x*256+threadIdx.x;
  if(idx>=B*N) return;
  int b=idx/N;
  float mu=st[b*2], var=st[b*2+1];
  float rs=rsqrtf(var+1e-8f);
  float xk[E];
  for(int e=0;e<E;e++) xk[e]=(x1[(size_t)idx*E+e]-mu)*rs;
  for(int k=0;k<E;k++){
    float a=0.f;
    for(int e=0;e<E;e++) a+=xk[e]*Wxabs[e*E+k];
    dew[(size_t)idx*E+k]=a;
  }
}

__global__ void k_adp(const float* __restrict__ dew, const float* __restrict__ x1,
                      float* __restrict__ adp){
  size_t idx=(size_t)blockIdx.x*256+threadIdx.x;
  if(idx>=(size_t)B*N*N) return;
  int m=(int)(idx%N); int n=(int)((idx/N)%N); int b=(int)(idx/((size_t)N*N));
  const float* dr=dew+((size_t)b*N+n)*E;
  const float* xr=x1+((size_t)b*N+m)*E;
  float a=0.f;
  for(int k=0;k<E;k++) a+=dr[k]*xr[k];
  adp[idx]=fmaxf(a,0.f);
}

// in-place: adp row -> softmax(adp*mask(top48)) row
__global__ void k_topk(float* __restrict__ adp){
  int row=blockIdx.x, tid=threadIdx.x;
  __shared__ float orig[N];
  __shared__ float work[N];
  __shared__ float rv[256];
  __shared__ int   ri[256];
  for(int i=tid;i<N;i+=256){ float v=adp[(size_t)row*N+i]; orig[i]=v; work[i]=v; }
  __syncthreads();
  for(int k=0;k<TOPK;k++){
    float bv=-1.f; int bi=N;
    for(int i=tid;i<N;i+=256){ float v=work[i]; if(v>bv){bv=v;bi=i;} }
    rv[tid]=bv; ri[tid]=bi; __syncthreads();
    for(int s=128;s>0;s>>=1){
      if(tid<s){
        if(rv[tid+s]>rv[tid] || (rv[tid+s]==rv[tid] && ri[tid+s]<ri[tid])){
          rv[tid]=rv[tid+s]; ri[tid]=ri[tid+s];
        }
      }
      __syncthreads();
    }
    if(tid==0) work[ri[0]] = -2.f;   // mark selected (orig values are >= 0)
    __syncthreads();
  }
  float lm=0.f;
  for(int i=tid;i<N;i+=256){ float p=(work[i]<-1.f)?orig[i]:0.f; lm=fmaxf(lm,p); }
  rv[tid]=lm; __syncthreads();
  for(int s=128;s>0;s>>=1){ if(tid<s) rv[tid]=fmaxf(rv[tid],rv[tid+s]); __syncthreads(); }
  float m=rv[0]; __syncthreads();
  float ls=0.f;
  for(int i=tid;i<N;i+=256){ float p=(work[i]<-1.f)?orig[i]:0.f; ls+=expf(p-m); }
  rv[tid]=ls; __syncthreads();
  for(int s=128;s>0;s>>=1){ if(tid<s) rv[tid]+=rv[tid+s]; __syncthreads(); }
  float invZ=1.0f/rv[0]; __syncthreads();
  for(int i=tid;i<N;i+=256){ float p=(work[i]<-1.f)?orig[i]:0.f; adp[(size_t)row*N+i]=expf(p-m)*invZ; }
}

// AdapT[w][v] = softmax_row(relu(E1@E2^T))[v][w]
__global__ void k_adap(const float* __restrict__ E1, const float* __restrict__ E2,
                       float* __restrict__ adapT){
  int v=blockIdx.x, tid=threadIdx.x;
  __shared__ float rowv[N];
  __shared__ float rv[256];
  float e1[E];
  for(int e=0;e<E;e++) e1[e]=E1[v*E+e];
  for(int j=tid;j<N;j+=256){
    float s=0.f;
    for(int e=0;e<E;e++) s+=e1[e]*E2[j*E+e];
    rowv[j]=fmaxf(s,0.f);
  }
  __syncthreads();
  float lm=-1e30f;
  for(int j=tid;j<N;j+=256) lm=fmaxf(lm,rowv[j]);
  rv[tid]=lm; __syncthreads();
  for(int s=128;s>0;s>>=1){ if(tid<s) rv[tid]=fmaxf(rv[tid],rv[tid+s]); __syncthreads(); }
  float m=rv[0]; __syncthreads();
  float ls=0.f;
  for(int j=tid;j<N;j+=256) ls+=expf(rowv[j]-m);
  rv[tid]=ls; __syncthreads();
  for(int s=128;s>0;s>>=1){ if(tid<s) rv[tid]+=rv[tid+s]; __syncthreads(); }
  float invZ=1.0f/rv[0];
  for(int j=tid;j<N;j+=256) adapT[(size_t)j*N+v]=expf(rowv[j]-m)*invZ;
}

__global__ void k_transNN(const float* __restrict__ src, float* __restrict__ dst){
  size_t idx=(size_t)blockIdx.x*256+threadIdx.x;
  if(idx>=(size_t)N*N) return;
  int j=(int)(idx%N), i=(int)(idx/N);
  dst[(size_t)j*N+i]=src[idx];
}

// ---------------- trunk ----------------
__global__ void k_start(const float* __restrict__ x, const float* __restrict__ sw,
                        const float* __restrict__ sb, float* __restrict__ h){
  int idx=blockIdx.x*256+threadIdx.x;
  if(idx>=B*C*N*T13) return;
  int t=idx%T13; int n=(idx/T13)%N; int o=(idx/(T13*N))%C; int b=idx/(T13*N*C);
  float a=sb[o];
  if(t>0){
    size_t xb=((size_t)(b*T+(t-1))*N+n)*CIN;
    for(int i=0;i<CIN;i++) a += sw[i*C+o]*x[xb+i];
  }
  h[idx]=a;
}

// fused per-(b,n): QKV proj + gelu + causal attention + FFN + residual
__global__ void k_attblock(const float* __restrict__ hin,
  const float* __restrict__ Wq, const float* __restrict__ bq,
  const float* __restrict__ Wk, const float* __restrict__ bk,
  const float* __restrict__ Wv, const float* __restrict__ bv,
  const float* __restrict__ W1, const float* __restrict__ b1,
  const float* __restrict__ W2, const float* __restrict__ b2,
  float* __restrict__ hout, int Tc){
  int bn=blockIdx.x; int tid=threadIdx.x;
  int n=bn%N, b=bn/N;
  __shared__ float sxa[T13*C];
  __shared__ float sq[T13*C];
  __shared__ float sk[T13*C];
  __shared__ float sv[T13*C];
  __shared__ float so[T13*C];
  __shared__ float shid[T13*4*C];
  const int TCC=Tc*C;
  for(int idx=tid; idx<TCC; idx+=256){
    int t=idx>>6, c=idx&63;
    sxa[idx]=hin[(((size_t)b*C+c)*N+n)*Tc+t];
  }
  __syncthreads();
  for(int idx=tid; idx<TCC; idx+=256){
    int t=idx>>6, o=idx&63;
    const float* xr=&sxa[t*C];
    float aq=bq[o], ak=bk[o], av=bv[o];
    for(int i=0;i<C;i++){ float xi=xr[i]; aq+=xi*Wq[i*C+o]; ak+=xi*Wk[i*C+o]; av+=xi*Wv[i*C+o]; }
    sq[idx]=geluf(aq); sk[idx]=geluf(ak); sv[idx]=geluf(av);
  }
  __syncthreads();
  if(tid<H*Tc){
    int hh=tid/Tc, t=tid%Tc;
    const float* qr=&sq[t*C+hh*HD];
    float att[T13];
    float m=-1e30f;
    for(int s=0;s<=t;s++){
      const float* kr=&sk[s*C+hh*HD];
      float a=0.f;
      #pragma unroll
      for(int d=0;d<HD;d++) a+=qr[d]*kr[d];
      a*=0.3535533905932738f;
      att[s]=a; m=fmaxf(m,a);
    }
    float Z=0.f;
    for(int s=0;s<=t;s++){ float e=expf(att[s]-m); att[s]=e; Z+=e; }
    float invZ=1.0f/Z;
    #pragma unroll
    for(int d=0;d<HD;d++){
      float o=0.f;
      for(int s=0;s<=t;s++) o+=att[s]*sv[s*C+hh*HD+d];
      so[t*C+hh*HD+d]=o*invZ;
    }
  }
  __syncthreads();
  for(int idx=tid; idx<Tc*4*C; idx+=256){
    int t=idx>>8, j=idx&255;
    const float* orow=&so[t*C];
    float a=b1[j];
    for(int i=0;i<C;i++) a+=orow[i]*W1[(size_t)i*4*C+j];
    shid[idx]=geluf(a);
  }
  __syncthreads();
  for(int idx=tid; idx<TCC; idx+=256){
    int t=idx>>6, o=idx&63;
    const float* hr=&shid[t*4*C];
    float a=b2[o];
    for(int j=0;j<4*C;j++) a+=hr[j]*W2[(size_t)j*C+o];
    size_t hi=(((size_t)b*C+o)*N+n)*Tc+t;
    hout[hi]=a+hin[hi];
  }
}

// gated dilated conv; writes transposed (b,n,c,tt) layout directly
__global__ void k_conv(const float* __restrict__ hin,
  const float* __restrict__ fw, const float* __restrict__ fb,
  const float* __restrict__ gw, const float* __restrict__ gb,
  float* __restrict__ hT, int Tc, int d){
  int gid=blockIdx.x; int c=threadIdx.x;
  int tn=Tc-d;
  int tt=gid%tn; int n=(gid/tn)%N; int b=gid/(tn*N);
  __shared__ float a0[C], a1[C];
  a0[c]=hin[(((size_t)b*C+c)*N+n)*Tc+tt];
  a1[c]=hin[(((size_t)b*C+c)*N+n)*Tc+tt+d];
  __syncthreads();
  float af=fb[c], ag=gb[c];
  for(int i=0;i<C;i++){
    af += fw[i*C+c]*a0[i] + fw[C*C+i*C+c]*a1[i];
    ag += gw[i*C+c]*a0[i] + gw[C*C+i*C+c]*a1[i];
  }
  hT[(((size_t)b*N+n)*C+c)*tn+tt]=tanhf(af)*sigmf(ag);
}

// skip projection — only the LAST time column ever reaches the head
__global__ void k_skiplast(const float* __restrict__ hT,
  const float* __restrict__ sw, const float* __restrict__ sb,
  float* __restrict__ skipacc, int tn, int first){
  int bn=blockIdx.x; int o=threadIdx.x;  // 256 threads
  int n=bn%N, b=bn/N;
  __shared__ float xr[C];
  if(o<C) xr[o]=hT[(((size_t)b*N+n)*C+o)*tn+(tn-1)];
  __syncthreads();
  float a=sb[o];
  for(int i=0;i<C;i++) a+=xr[i]*sw[i*SKC+o];
  size_t oi=((size_t)b*SKC+o)*N+n;
  if(first) skipacc[oi]=a; else skipacc[oi]+=a;
}

// Y[b] = A'(b) @ X[b];  A' is NxN row-major [w][v]; X,Y are (B,N,M)
__global__ void k_spatial(const float* __restrict__ A, long long aStride,
                          const float* __restrict__ X, float* __restrict__ Y, int M){
  __shared__ float As[32][33];
  __shared__ float Bs[32][33];
  int b=blockIdx.z;
  const float* Ab=A+(size_t)b*aStride;
  const float* Xb=X+(size_t)b*N*M;
  float* Yb=Y+(size_t)b*N*M;
  int tid=threadIdx.x;
  int tx=tid&15, ty=tid>>4;
  int rowBase=blockIdx.x*32, colBase=blockIdx.y*32;
  float a00=0.f,a01=0.f,a10=0.f,a11=0.f;
  for(int k0=0;k0<N;k0+=32){
    #pragma unroll
    for(int e=0;e<4;e++){
      int li=tid+e*256; int i=li>>5, j=li&31;
      int ar=rowBase+i, ac=k0+j;
      As[i][j]=(ar<N&&ac<N)?Ab[(size_t)ar*N+ac]:0.f;
      int br=k0+i, bc=colBase+j;
      Bs[i][j]=(br<N&&bc<M)?Xb[(size_t)br*M+bc]:0.f;
    }
    __syncthreads();
    #pragma unroll
    for(int kk=0;kk<32;kk++){
      float av0=As[ty][kk], av1=As[ty+16][kk];
      float bv0=Bs[kk][tx], bv1=Bs[kk][tx+16];
      a00+=av0*bv0; a01+=av0*bv1; a10+=av1*bv0; a11+=av1*bv1;
    }
    __syncthreads();
  }
  int r0=rowBase+ty, c0=colBase+tx;
  if(r0<N){
    if(c0<M)    Yb[(size_t)r0*M+c0]=a00;
    if(c0+16<M) Yb[(size_t)r0*M+c0+16]=a01;
  }
  if(r0+16<N){
    if(c0<M)    Yb[(size_t)(r0+16)*M+c0]=a10;
    if(c0+16<M) Yb[(size_t)(r0+16)*M+c0+16]=a11;
  }
}

// init: acc = gcn_b + residual(pH tail) + hT @ W0
__global__ void k_gcn0(const float* __restrict__ hT, const float* __restrict__ Wc,
                       const float* __restrict__ gb, const float* __restrict__ res,
                       float* __restrict__ acc, int Tc, int tn){
  int gid=blockIdx.x; int o=threadIdx.x;  // 64 threads
  int tt=gid%tn; int n=(gid/tn)%N; int b=gid/(tn*N);
  __shared__ float xr[C];
  xr[o]=hT[(((size_t)b*N+n)*C+o)*tn+tt];
  __syncthreads();
  float a=gb[o]+res[(((size_t)b*C+o)*N+n)*Tc+(Tc-tn)+tt];
  for(int i=0;i<C;i++) a+=xr[i]*Wc[i*C+o];
  acc[(((size_t)b*C+o)*N+n)*tn+tt]=a;
}

// acc += xT @ Wc
__global__ void k_gcnacc(const float* __restrict__ xT, const float* __restrict__ Wc,
                         float* __restrict__ acc, int tn){
  int gid=blockIdx.x; int o=threadIdx.x;  // 64 threads
  int tt=gid%tn; int n=(gid/tn)%N; int b=gid/(tn*N);
  __shared__ float xr[C];
  xr[o]=xT[(((size_t)b*N+n)*C+o)*tn+tt];
  __syncthreads();
  float a=0.f;
  for(int i=0;i<C;i++) a+=xr[i]*Wc[i*C+o];
  acc[(((size_t)b*C+o)*N+n)*tn+tt]+=a;
}

__global__ void k_bnstats(const float* __restrict__ h, float* __restrict__ st, int tn){
  int c=blockIdx.x, tid=threadIdx.x;
  __shared__ float rs[256], rq[256];
  const int Mi=N*tn;
  const int M=B*Mi;
  float s=0.f,q=0.f;
  for(int idx=tid; idx<M; idx+=256){
    int b=idx/Mi; int inner=idx%Mi;
    float v=h[(size_t)b*C*Mi + (size_t)c*Mi + inner];
    s+=v; q+=v*v;
  }
  rs[tid]=s; rq[tid]=q; __syncthreads();
  for(int k=128;k>0;k>>=1){ if(tid<k){ rs[tid]+=rs[tid+k]; rq[tid]+=rq[tid+k]; } __syncthreads(); }
  if(tid==0){
    float mu=rs[0]/M; float var=rq[0]/M-mu*mu;
    st[c]=mu; st[C+c]=rsqrtf(var+1e-5f);
  }
}

__global__ void k_bnapply(float* __restrict__ h, const float* __restrict__ st,
                          const float* __restrict__ g, const float* __restrict__ bb, int tn){
  int idx=blockIdx.x*256+threadIdx.x;
  if(idx>=B*C*N*tn) return;
  int c=(idx/(N*tn))%C;
  float v=h[idx];
  h[idx]=(v-st[c])*st[C+c]*g[c]+bb[c];
}

__global__ void k_head(const float* __restrict__ skipacc, const float* __restrict__ W1,
  const float* __restrict__ b1, const float* __restrict__ W2, const float* __restrict__ b2,
  float* __restrict__ out){
  int gid=blockIdx.x; int tid=threadIdx.x;  // 512 threads
  int n=gid%N; int b=gid/N;
  __shared__ float s[SKC];
  __shared__ float hid[512];
  if(tid<SKC){
    float v=skipacc[((size_t)b*SKC+tid)*N+n];
    s[tid]=fmaxf(v,0.f);
  }
  __syncthreads();
  {
    float a=b1[tid];
    for(int i=0;i<SKC;i++) a+=s[i]*W1[(size_t)i*512+tid];
    hid[tid]=fmaxf(a,0.f);
  }
  __syncthreads();
  if(tid<T){
    float a=b2[tid];
    for(int j=0;j<512;j++) a+=hid[j]*W2[(size_t)j*T+tid];
    out[((size_t)b*T+tid)*N+n]=a;
  }
}

} // namespace

extern "C" void kernel_launch(void* const* d_in, const int* in_sizes, int n_in,
                              void* d_out, int out_size, void* d_ws, size_t ws_size,
                              hipStream_t stream){
  (void)in_sizes; (void)n_in;
  const float* x      =(const float*)d_in[0];
  const float* sup0   =(const float*)d_in[1];
  const float* sup1   =(const float*)d_in[2];
  const float* TiD    =(const float*)d_in[3];
  const float* DiW    =(const float*)d_in[4];
  const float* E1     =(const float*)d_in[5];
  const float* E2     =(const float*)d_in[6];
  const float* E3     =(const float*)d_in[7];
  const float* Wx     =(const float*)d_in[8];
  const float* Wd     =(const float*)d_in[9];
  const float* Wxabs  =(const float*)d_in[10];
  const float* start_w=(const float*)d_in[11];
  const float* start_b=(const float*)d_in[12];
  const float* Wq     =(const float*)d_in[13];
  const float* bq     =(const float*)d_in[14];
  const float* Wk     =(const float*)d_in[15];
  const float* bk     =(const float*)d_in[16];
  const float* Wv     =(const float*)d_in[17];
  const float* bv     =(const float*)d_in[18];
  const float* W1     =(const float*)d_in[19];
  const float* b1     =(const float*)d_in[20];
  const float* W2     =(const float*)d_in[21];
  const float* b2     =(const float*)d_in[22];
  const float* filt_w =(const float*)d_in[23];
  const float* filt_b =(const float*)d_in[24];
  const float* gate_w =(const float*)d_in[25];
  const float* gate_b =(const float*)d_in[26];
  const float* skip_w =(const float*)d_in[27];
  const float* skip_b =(const float*)d_in[28];
  const float* gcn_w  =(const float*)d_in[29];
  const float* gcn_b  =(const float*)d_in[30];
  const float* bn_g   =(const float*)d_in[31];
  const float* bn_b   =(const float*)d_in[32];
  const float* end1_w =(const float*)d_in[33];
  const float* end1_b =(const float*)d_in[34];
  const float* end2_w =(const float*)d_in[35];
  const float* end2_b =(const float*)d_in[36];

  // workspace carve (floats)
  const size_t HMAX =(size_t)B*C*N*T13;   // 5,877,248
  const size_t HT12 =(size_t)B*C*N*12;    // 5,425,152
  size_t need_f = 0;
  need_f += (size_t)B*F7*N;         // xf
  need_f += (size_t)B*N*E;          // gx1
  need_f += (size_t)B*N*E;          // gdew
  need_f += 16;                     // gst
  need_f += 2*C;                    // bnst
  need_f += (size_t)B*N*N;          // adpAD
  need_f += 3*(size_t)N*N;          // adapT, s0T, s1T
  need_f += 2*HMAX;                 // pH, pAlt
  need_f += 3*HT12;                 // hT, P, Q
  need_f += (size_t)B*SKC*N;        // skipacc
  if(ws_size < need_f*sizeof(float)){
    // workspace too small: fail cleanly (diagnostic: absmax == max|ref|)
    hipMemsetAsync(d_out, 0, (size_t)out_size*sizeof(float), stream);
    return;
  }

  size_t off=0;
  auto alloc=[&](size_t nf)->float*{
    float* p=(float*)((char*)d_ws+off);
    off += nf*sizeof(float);
    return p;
  };
  float* xf     = alloc((size_t)B*F7*N);
  float* gx1    = alloc((size_t)B*N*E);
  float* gdew   = alloc((size_t)B*N*E);
  float* gst    = alloc(16);
  float* bnst   = alloc(2*C);
  float* adpAD  = alloc((size_t)B*N*N);
  float* adapT  = alloc((size_t)N*N);
  float* s0T    = alloc((size_t)N*N);
  float* s1T    = alloc((size_t)N*N);
  float* pH     = alloc(HMAX);
  float* pAlt   = alloc(HMAX);
  float* hT     = alloc(HT12);
  float* Pb     = alloc(HT12);
  float* Qb     = alloc(HT12);
  float* skipacc= alloc((size_t)B*SKC*N);

  // ---- graph generation ----
  k_dft <<<DIVUP(B*F7*N,256),256,0,stream>>>(x, xf);
  k_l2f <<<DIVUP(B*N,256),256,0,stream>>>(xf);
  k_l2n <<<B*F7,256,0,stream>>>(xf);
  k_x1  <<<DIVUP(B*N,256),256,0,stream>>>(x, xf, E3, TiD, DiW, Wx, Wd, gx1);
  k_lnstats<<<B,256,0,stream>>>(gx1, gst);
  k_dew <<<DIVUP(B*N,256),256,0,stream>>>(gx1, gst, Wxabs, gdew);
  k_adp <<<DIVUP(B*N*N,256),256,0,stream>>>(gdew, gx1, adpAD);
  k_topk<<<B*N,256,0,stream>>>(adpAD);
  k_adap<<<N,256,0,stream>>>(E1, E2, adapT);
  k_transNN<<<DIVUP(N*N,256),256,0,stream>>>(sup0, s0T);
  k_transNN<<<DIVUP(N*N,256),256,0,stream>>>(sup1, s1T);

  // ---- trunk ----
  k_start<<<DIVUP(B*C*N*T13,256),256,0,stream>>>(x, start_w, start_b, pH);

  int Tc=T13;
  const int DILa[L]={1,2,1,2,1,2,1,2};
  for(int l=0;l<L;l++){
    int d=DILa[l]; int tn=Tc-d;
    k_attblock<<<B*N,256,0,stream>>>(pH,
        Wq+(size_t)l*C*C, bq+(size_t)l*C,
        Wk+(size_t)l*C*C, bk+(size_t)l*C,
        Wv+(size_t)l*C*C, bv+(size_t)l*C,
        W1+(size_t)l*C*4*C, b1+(size_t)l*4*C,
        W2+(size_t)l*4*C*C, b2+(size_t)l*C,
        pAlt, Tc);
    k_conv<<<B*N*tn,64,0,stream>>>(pAlt,
        filt_w+(size_t)l*2*C*C, filt_b+(size_t)l*C,
        gate_w+(size_t)l*2*C*C, gate_b+(size_t)l*C,
        hT, Tc, d);
    k_skiplast<<<B*N,256,0,stream>>>(hT,
        skip_w+(size_t)l*C*SKC, skip_b+(size_t)l*SKC, skipacc, tn, l==0?1:0);
    if(l<L-1){  // last layer's GCN/BN output is dead (only skip feeds the head)
      k_gcn0<<<B*N*tn,64,0,stream>>>(hT,
          gcn_w+((size_t)l*9*C)*C, gcn_b+(size_t)l*C, pH, pAlt, Tc, tn);
      const float* Aps[4]={s0T, s1T, adapT, adpAD};
      const long long Ast[4]={0,0,0,(long long)N*N};
      int M=C*tn;
      dim3 sg(DIVUP(N,32), DIVUP(M,32), B);
      for(int s=0;s<4;s++){
        k_spatial<<<sg,256,0,stream>>>(Aps[s], Ast[s], hT, Pb, M);
        k_gcnacc<<<B*N*tn,64,0,stream>>>(Pb,
            gcn_w+((size_t)l*9*C+(size_t)(1+2*s)*C)*C, pAlt, tn);
        k_spatial<<<sg,256,0,stream>>>(Aps[s], Ast[s], Pb, Qb, M);
        k_gcnacc<<<B*N*tn,64,0,stream>>>(Qb,
            gcn_w+((size_t)l*9*C+(size_t)(2+2*s)*C)*C, pAlt, tn);
      }
      k_bnstats<<<C,256,0,stream>>>(pAlt, bnst, tn);
      k_bnapply<<<DIVUP(B*C*N*tn,256),256,0,stream>>>(pAlt, bnst,
          bn_g+(size_t)l*C, bn_b+(size_t)l*C, tn);
      float* tmp=pH; pH=pAlt; pAlt=tmp;
    }
    Tc=tn;
  }

  k_head<<<B*N,512,0,stream>>>(skipacc, end1_w, end1_b, end2_w, end2_b, (float*)d_out);
}

// Round 4
// 14112.659 us; speedup vs baseline: 3.2411x; 3.2411x over previous
//
#include <hip/hip_runtime.h>
#include <math.h>

#define DIVUP(a,b) (((a)+(b)-1)/(b))

namespace {

constexpr int B=8, T=12, N=883, CIN=3, C=64, E=10, H=8, HD=8, TOPK=48, L=8;
constexpr int SKC=256, F7=7, T13=13;

__device__ __forceinline__ float geluf(float x){ return 0.5f*x*(1.0f+erff(x*0.7071067811865475f)); }
__device__ __forceinline__ float sigmf(float x){ return 1.0f/(1.0f+expf(-x)); }

// ---------------- graph generation ----------------
__global__ void k_dft(const float* __restrict__ x, float* __restrict__ xf){
  int idx = blockIdx.x*256 + threadIdx.x;
  if(idx >= B*F7*N) return;
  int n = idx % N; int f = (idx/N) % F7; int b = idx/(N*F7);
  float re=0.f, im=0.f;
  for(int t=0;t<T;t++){
    float v = x[((size_t)(b*T+t)*N+n)*CIN];
    float ang = -6.283185307179586f * (float)(f*t) / 12.0f;
    re += v*cosf(ang); im += v*sinf(ang);
  }
  xf[idx] = sqrtf(re*re+im*im);
}

__global__ void k_l2f(float* __restrict__ xf){
  int idx = blockIdx.x*256 + threadIdx.x;
  if(idx >= B*N) return;
  int n = idx % N; int b = idx / N;
  float s=0.f;
  for(int f=0;f<F7;f++){ float v=xf[((size_t)b*F7+f)*N+n]; s+=v*v; }
  float inv = 1.0f/fmaxf(sqrtf(s), 1e-12f);
  for(int f=0;f<F7;f++) xf[((size_t)b*F7+f)*N+n] *= inv;
}

__global__ void k_l2n(float* __restrict__ xf){
  int bf = blockIdx.x; int tid = threadIdx.x;
  __shared__ float red[256];
  size_t base = (size_t)bf*N;
  float s=0.f;
  for(int i=tid;i<N;i+=256){ float v=xf[base+i]; s+=v*v; }
  red[tid]=s; __syncthreads();
  for(int k=128;k>0;k>>=1){ if(tid<k) red[tid]+=red[tid+k]; __syncthreads(); }
  float inv = 1.0f/fmaxf(sqrtf(red[0]), 1e-12f);
  __syncthreads();
  for(int i=tid;i<N;i+=256) xf[base+i]*=inv;
}

__global__ void k_x1(const float* __restrict__ x, const float* __restrict__ xf,
                     const float* __restrict__ E3, const float* __restrict__ TiD,
                     const float* __restrict__ DiW, const float* __restrict__ Wx,
                     const float* __restrict__ Wd, float* __restrict__ x1){
  int idx = blockIdx.x*256+threadIdx.x;
  if(idx>=B*N) return;
  int n=idx%N, b=idx/N;
  float xc[40];
  for(int d=0;d<E;d++){
    float a=0.f;
    for(int f=0;f<F7;f++) a += xf[((size_t)b*F7+f)*N+n]*Wx[f*E+d];
    xc[d]=a;
  }
  for(int d=0;d<E;d++) xc[10+d]=E3[n*E+d];
  int ti = (int)(x[((size_t)(b*T+(T-1))*N+n)*CIN+1]*288.0f);
  int dw = (int)(x[((size_t)(b*T+(T-1))*N+n)*CIN+2]);
  for(int d=0;d<E;d++) xc[20+d]=TiD[ti*E+d];
  for(int d=0;d<E;d++) xc[30+d]=DiW[dw*E+d];
  for(int e=0;e<E;e++){
    float a=0.f;
    for(int f=0;f<40;f++) a += xc[f]*Wd[((size_t)n*40+f)*E+e];
    x1[(size_t)idx*E+e]=fmaxf(a,0.f);
  }
}

__global__ void k_lnstats(const float* __restrict__ x1, float* __restrict__ st){
  int b=blockIdx.x, tid=threadIdx.x;
  __shared__ float rs[256], rq[256];
  const int M=N*E;
  float s=0.f,q=0.f;
  for(int i=tid;i<M;i+=256){ float v=x1[(size_t)b*M+i]; s+=v; q+=v*v; }
  rs[tid]=s; rq[tid]=q; __syncthreads();
  for(int k=128;k>0;k>>=1){ if(tid<k){ rs[tid]+=rs[tid+k]; rq[tid]+=rq[tid+k]; } __syncthreads(); }
  if(tid==0){ float mu=rs[0]/M; float var=rq[0]/M-mu*mu; st[b*2]=mu; st[b*2+1]=var; }
}

__global__ void k_dew(const float* __restrict__ x1, const float* __restrict__ st,
                      const float* __restrict__ Wxabs, float* __restrict__ dew){
  int idx=blockIdx.x*256+threadIdx.x;
  if(idx>=B*N) return;
  int b=idx/N;
  float mu=st[b*2], var=st[b*2+1];
  float rs=rsqrtf(var+1e-8f);
  float xk[E];
  for(int e=0;e<E;e++) xk[e]=(x1[(size_t)idx*E+e]-mu)*rs;
  for(int k=0;k<E;k++){
    float a=0.f;
    for(int e=0;e<E;e++) a+=xk[e]*Wxabs[e*E+k];
    dew[(size_t)idx*E+k]=a;
  }
}

__global__ void k_adp(const float* __restrict__ dew, const float* __restrict__ x1,
                      float* __restrict__ adp){
  size_t idx=(size_t)blockIdx.x*256+threadIdx.x;
  if(idx>=(size_t)B*N*N) return;
  int m=(int)(idx%N); int n=(int)((idx/N)%N); int b=(int)(idx/((size_t)N*N));
  const float* dr=dew+((size_t)b*N+n)*E;
  const float* xr=x1+((size_t)b*N+m)*E;
  float a=0.f;
  for(int k=0;k<E;k++) a+=dr[k]*xr[k];
  adp[idx]=fmaxf(a,0.f);
}

__global__ void k_topk(float* __restrict__ adp){
  int row=blockIdx.x, tid=threadIdx.x;
  __shared__ float orig[N];
  __shared__ float work[N];
  __shared__ float rv[256];
  __shared__ int   ri[256];
  for(int i=tid;i<N;i+=256){ float v=adp[(size_t)row*N+i]; orig[i]=v; work[i]=v; }
  __syncthreads();
  for(int k=0;k<TOPK;k++){
    float bv=-1.f; int bi=N;
    for(int i=tid;i<N;i+=256){ float v=work[i]; if(v>bv){bv=v;bi=i;} }
    rv[tid]=bv; ri[tid]=bi; __syncthreads();
    for(int s=128;s>0;s>>=1){
      if(tid<s){
        if(rv[tid+s]>rv[tid] || (rv[tid+s]==rv[tid] && ri[tid+s]<ri[tid])){
          rv[tid]=rv[tid+s]; ri[tid]=ri[tid+s];
        }
      }
      __syncthreads();
    }
    if(tid==0) work[ri[0]] = -2.f;
    __syncthreads();
  }
  float lm=0.f;
  for(int i=tid;i<N;i+=256){ float p=(work[i]<-1.f)?orig[i]:0.f; lm=fmaxf(lm,p); }
  rv[tid]=lm; __syncthreads();
  for(int s=128;s>0;s>>=1){ if(tid<s) rv[tid]=fmaxf(rv[tid],rv[tid+s]); __syncthreads(); }
  float m=rv[0]; __syncthreads();
  float ls=0.f;
  for(int i=tid;i<N;i+=256){ float p=(work[i]<-1.f)?orig[i]:0.f; ls+=expf(p-m); }
  rv[tid]=ls; __syncthreads();
  for(int s=128;s>0;s>>=1){ if(tid<s) rv[tid]+=rv[tid+s]; __syncthreads(); }
  float invZ=1.0f/rv[0]; __syncthreads();
  for(int i=tid;i<N;i+=256){ float p=(work[i]<-1.f)?orig[i]:0.f; adp[(size_t)row*N+i]=expf(p-m)*invZ; }
}

__global__ void k_adap(const float* __restrict__ E1, const float* __restrict__ E2,
                       float* __restrict__ adapT){
  int v=blockIdx.x, tid=threadIdx.x;
  __shared__ float rowv[N];
  __shared__ float rv[256];
  float e1[E];
  for(int e=0;e<E;e++) e1[e]=E1[v*E+e];
  for(int j=tid;j<N;j+=256){
    float s=0.f;
    for(int e=0;e<E;e++) s+=e1[e]*E2[j*E+e];
    rowv[j]=fmaxf(s,0.f);
  }
  __syncthreads();
  float lm=-1e30f;
  for(int j=tid;j<N;j+=256) lm=fmaxf(lm,rowv[j]);
  rv[tid]=lm; __syncthreads();
  for(int s=128;s>0;s>>=1){ if(tid<s) rv[tid]=fmaxf(rv[tid],rv[tid+s]); __syncthreads(); }
  float m=rv[0]; __syncthreads();
  float ls=0.f;
  for(int j=tid;j<N;j+=256) ls+=expf(rowv[j]-m);
  rv[tid]=ls; __syncthreads();
  for(int s=128;s>0;s>>=1){ if(tid<s) rv[tid]+=rv[tid+s]; __syncthreads(); }
  float invZ=1.0f/rv[0];
  for(int j=tid;j<N;j+=256) adapT[(size_t)j*N+v]=expf(rowv[j]-m)*invZ;
}

__global__ void k_transNN(const float* __restrict__ src, float* __restrict__ dst){
  size_t idx=(size_t)blockIdx.x*256+threadIdx.x;
  if(idx>=(size_t)N*N) return;
  int j=(int)(idx%N), i=(int)(idx/N);
  dst[(size_t)j*N+i]=src[idx];
}

// ---------------- trunk ----------------
__global__ void k_start(const float* __restrict__ x, const float* __restrict__ sw,
                        const float* __restrict__ sb, float* __restrict__ h){
  int idx=blockIdx.x*256+threadIdx.x;
  if(idx>=B*C*N*T13) return;
  int t=idx%T13; int n=(idx/T13)%N; int o=(idx/(T13*N))%C; int b=idx/(T13*N*C);
  float a=sb[o];
  if(t>0){
    size_t xb=((size_t)(b*T+(t-1))*N+n)*CIN;
    for(int i=0;i<CIN;i++) a += sw[i*C+o]*x[xb+i];
  }
  h[idx]=a;
}

// Fused per-(b,n): QKV+gelu+causal attn+FFN+residual+gated dilated conv.
// Writes ONLY hT (conv output, [b][n][c][tt] contiguous per (b,n)).
template<int TC, int D>
__global__ __launch_bounds__(256) void k_attconv(const float* __restrict__ hin,
  const float* __restrict__ Wq, const float* __restrict__ bq,
  const float* __restrict__ Wk, const float* __restrict__ bk,
  const float* __restrict__ Wv, const float* __restrict__ bv,
  const float* __restrict__ W1, const float* __restrict__ b1,
  const float* __restrict__ W2, const float* __restrict__ b2,
  const float* __restrict__ fw, const float* __restrict__ fb,
  const float* __restrict__ gw, const float* __restrict__ gb,
  float* __restrict__ hT){
  constexpr int TN = TC - D;
  int bn=blockIdx.x; int tid=threadIdx.x;
  int n=bn%N, b=bn/N;
  __shared__ float sxa [T13*C];
  __shared__ float sq  [T13*C];
  __shared__ float sk  [T13*C];
  __shared__ float sv  [T13*C];
  __shared__ float so  [T13*C];
  __shared__ float shid[T13*4*C];

  // load layer input slice
  for(int idx=tid; idx<TC*C; idx+=256){
    int c=idx/TC, t=idx%TC;
    sxa[t*C+c]=hin[(((size_t)b*C+c)*N+n)*TC+t];
  }
  __syncthreads();

  // QKV projection + gelu: 192 threads, acc[TC] register reuse
  if(tid<192){
    int m=tid>>6, o=tid&63;
    const float* Wm=(m==0)?Wq:((m==1)?Wk:Wv);
    const float* bm=(m==0)?bq:((m==1)?bk:bv);
    float acc[TC];
    #pragma unroll
    for(int t=0;t<TC;t++) acc[t]=bm[o];
    for(int i=0;i<C;i++){
      float w=Wm[i*C+o];
      #pragma unroll
      for(int t=0;t<TC;t++) acc[t]+=w*sxa[t*C+i];
    }
    float* dst=(m==0)?sq:((m==1)?sk:sv);
    #pragma unroll
    for(int t=0;t<TC;t++) dst[t*C+o]=geluf(acc[t]);
  }
  __syncthreads();

  // causal attention: thread per (head,t)
  if(tid<H*TC){
    int hh=tid/TC, t=tid%TC;
    const float* qr=&sq[t*C+hh*HD];
    float att[TC];
    float m=-1e30f;
    #pragma unroll
    for(int s=0;s<TC;s++){
      float a=0.f;
      #pragma unroll
      for(int d=0;d<HD;d++) a+=qr[d]*sk[s*C+hh*HD+d];
      a*=0.3535533905932738f;
      a=(s<=t)?a:-1e30f;
      att[s]=a; m=fmaxf(m,a);
    }
    float Z=0.f;
    #pragma unroll
    for(int s=0;s<TC;s++){ float e=expf(att[s]-m); att[s]=e; Z+=e; }
    float invZ=1.0f/Z;
    #pragma unroll
    for(int d=0;d<HD;d++){
      float o=0.f;
      #pragma unroll
      for(int s=0;s<TC;s++) o+=att[s]*sv[s*C+hh*HD+d];
      so[t*C+hh*HD+d]=o*invZ;
    }
  }
  __syncthreads();

  // FFN1: 256 outputs, acc[TC] register reuse
  {
    int j=tid;
    float acc[TC];
    #pragma unroll
    for(int t=0;t<TC;t++) acc[t]=b1[j];
    for(int i=0;i<C;i++){
      float w=W1[(size_t)i*4*C+j];
      #pragma unroll
      for(int t=0;t<TC;t++) acc[t]+=w*so[t*C+i];
    }
    #pragma unroll
    for(int t=0;t<TC;t++) shid[t*4*C+j]=geluf(acc[t]);
  }
  __syncthreads();

  // FFN2: K=256 split over 4 parts of 64
  {
    int o=tid&63, part=tid>>6;
    float acc[TC];
    #pragma unroll
    for(int t=0;t<TC;t++) acc[t]=(part==0)?b2[o]:0.f;
    for(int jj=0;jj<64;jj++){
      int j=part*64+jj;
      float w=W2[(size_t)j*C+o];
      #pragma unroll
      for(int t=0;t<TC;t++) acc[t]+=w*shid[t*4*C+j];
    }
    if(part==1){
      #pragma unroll
      for(int t=0;t<TC;t++) sq[t*C+o]=acc[t];
    }else if(part==2){
      #pragma unroll
      for(int t=0;t<TC;t++) sk[t*C+o]=acc[t];
    }else if(part==3){
      #pragma unroll
      for(int t=0;t<TC;t++) sv[t*C+o]=acc[t];
    }
    __syncthreads();
    if(part==0){
      #pragma unroll
      for(int t=0;t<TC;t++){
        float fin=acc[t]+sq[t*C+o]+sk[t*C+o]+sv[t*C+o]+sxa[t*C+o];
        shid[t*C+o]=fin;   // reuse shid[0..TC*C) as conv input
      }
    }
  }
  __syncthreads();

  // gated dilated conv on shid[0..TC*C)
  if(tid<128){
    int c=tid&63, m=tid>>6;
    const float* base=m?gw:fw;
    float acc[TN];
    #pragma unroll
    for(int tt=0;tt<TN;tt++) acc[tt]=0.f;
    for(int i=0;i<C;i++){
      float w0=base[i*C+c];
      float w1=base[C*C+i*C+c];
      #pragma unroll
      for(int tt=0;tt<TN;tt++) acc[tt]+=w0*shid[tt*C+i]+w1*shid[(tt+D)*C+i];
    }
    float bi=m?gb[c]:fb[c];
    if(m==0){
      #pragma unroll
      for(int tt=0;tt<TN;tt++) sq[tt*C+c]=tanhf(acc[tt]+bi);
    }else{
      #pragma unroll
      for(int tt=0;tt<TN;tt++) sk[tt*C+c]=sigmf(acc[tt]+bi);
    }
  }
  __syncthreads();

  // coalesced hT write: [b][n][c][tt]
  size_t obase=(size_t)bn*C*TN;
  for(int idx=tid; idx<C*TN; idx+=256){
    int c=idx/TN, tt=idx%TN;
    hT[obase+idx]=sq[tt*C+c]*sk[tt*C+c];
  }
}

__global__ void k_skiplast(const float* __restrict__ hT,
  const float* __restrict__ sw, const float* __restrict__ sb,
  float* __restrict__ skipacc, int tn, int first){
  int bn=blockIdx.x; int o=threadIdx.x;  // 256 threads
  int n=bn%N, b=bn/N;
  __shared__ float xr[C];
  if(o<C) xr[o]=hT[(((size_t)b*N+n)*C+o)*tn+(tn-1)];
  __syncthreads();
  float a=sb[o];
  for(int i=0;i<C;i++) a+=xr[i]*sw[i*SKC+o];
  size_t oi=((size_t)b*SKC+o)*N+n;
  if(first) skipacc[oi]=a; else skipacc[oi]+=a;
}

// Y[b] = A'(b) @ X[b]; A' NxN row-major [w][v]; X,Y (B,N,M), M % 64 == 0
__global__ __launch_bounds__(256) void k_spatial(
    const float* __restrict__ A, long long aStride,
    const float* __restrict__ X, float* __restrict__ Y, int M){
  __shared__ float As[64][68];   // [row][k]
  __shared__ float Bs[64][68];   // [k][col]
  int b=blockIdx.z;
  const float* Ab=A+(size_t)b*aStride;
  const float* Xb=X+(size_t)b*N*M;
  float* Yb=Y+(size_t)b*N*M;
  int tid=threadIdx.x;
  int lrow=tid>>6, lcol=tid&63;
  int tx=tid&15, ty=tid>>4;
  int rowBase=blockIdx.x*64, colBase=blockIdx.y*64;
  float acc[4][4];
  #pragma unroll
  for(int i=0;i<4;i++){
    #pragma unroll
    for(int j=0;j<4;j++) acc[i][j]=0.f;
  }
  for(int k0=0;k0<N;k0+=64){
    #pragma unroll
    for(int e=0;e<16;e++){
      int row=lrow+e*4;
      int ar=rowBase+row, ak=k0+lcol;
      As[row][lcol]=(ar<N&&ak<N)?Ab[(size_t)ar*N+ak]:0.f;
      int bk=k0+row;
      Bs[row][lcol]=(bk<N)?Xb[(size_t)bk*M+colBase+lcol]:0.f;
    }
    __syncthreads();
    #pragma unroll 4
    for(int kk=0;kk<64;kk++){
      float4 bv=*(const float4*)&Bs[kk][tx*4];
      float a0=As[ty*4+0][kk], a1=As[ty*4+1][kk], a2=As[ty*4+2][kk], a3=As[ty*4+3][kk];
      acc[0][0]+=a0*bv.x; acc[0][1]+=a0*bv.y; acc[0][2]+=a0*bv.z; acc[0][3]+=a0*bv.w;
      acc[1][0]+=a1*bv.x; acc[1][1]+=a1*bv.y; acc[1][2]+=a1*bv.z; acc[1][3]+=a1*bv.w;
      acc[2][0]+=a2*bv.x; acc[2][1]+=a2*bv.y; acc[2][2]+=a2*bv.z; acc[2][3]+=a2*bv.w;
      acc[3][0]+=a3*bv.x; acc[3][1]+=a3*bv.y; acc[3][2]+=a3*bv.z; acc[3][3]+=a3*bv.w;
    }
    __syncthreads();
  }
  #pragma unroll
  for(int i=0;i<4;i++){
    int r=rowBase+ty*4+i;
    if(r<N){
      float4 v; v.x=acc[i][0]; v.y=acc[i][1]; v.z=acc[i][2]; v.w=acc[i][3];
      *(float4*)&Yb[(size_t)r*M+colBase+tx*4]=v;
    }
  }
}

// acc = gcn_b + residual(pH tail) + hT @ W0  (per (b,n) block, 64 threads)
template<int TN>
__global__ void k_gcn0(const float* __restrict__ hT, const float* __restrict__ Wc,
                       const float* __restrict__ gb, const float* __restrict__ res,
                       float* __restrict__ acc, int Tc){
  int bn=blockIdx.x; int o=threadIdx.x;
  int n=bn%N, b=bn/N;
  __shared__ float sx[C*TN];
  size_t base=(size_t)bn*C*TN;
  for(int idx=o; idx<C*TN; idx+=64) sx[idx]=hT[base+idx];
  __syncthreads();
  float a[TN];
  #pragma unroll
  for(int tt=0;tt<TN;tt++) a[tt]=0.f;
  for(int i=0;i<C;i++){
    float w=Wc[i*C+o];
    #pragma unroll
    for(int tt=0;tt<TN;tt++) a[tt]+=w*sx[i*TN+tt];
  }
  size_t rbase=(((size_t)b*C+o)*N+n)*Tc+(Tc-TN);
  size_t obase=(((size_t)b*C+o)*N+n)*TN;
  float g=gb[o];
  #pragma unroll
  for(int tt=0;tt<TN;tt++) acc[obase+tt]=a[tt]+g+res[rbase+tt];
}

// acc += xT @ Wc
template<int TN>
__global__ void k_gcnacc(const float* __restrict__ xT, const float* __restrict__ Wc,
                         float* __restrict__ acc){
  int bn=blockIdx.x; int o=threadIdx.x;
  __shared__ float sx[C*TN];
  size_t base=(size_t)bn*C*TN;
  for(int idx=o; idx<C*TN; idx+=64) sx[idx]=xT[base+idx];
  __syncthreads();
  float a[TN];
  #pragma unroll
  for(int tt=0;tt<TN;tt++) a[tt]=0.f;
  for(int i=0;i<C;i++){
    float w=Wc[i*C+o];
    #pragma unroll
    for(int tt=0;tt<TN;tt++) a[tt]+=w*sx[i*TN+tt];
  }
  int n=bn%N, b=bn/N;
  size_t obase=(((size_t)b*C+o)*N+n)*TN;
  #pragma unroll
  for(int tt=0;tt<TN;tt++) acc[obase+tt]+=a[tt];
}

__global__ void k_bnstats(const float* __restrict__ h, float* __restrict__ st, int tn){
  int c=blockIdx.x, tid=threadIdx.x;
  __shared__ float rs[256], rq[256];
  const int Mi=N*tn;
  const int M=B*Mi;
  float s=0.f,q=0.f;
  for(int idx=tid; idx<M; idx+=256){
    int b=idx/Mi; int inner=idx%Mi;
    float v=h[(size_t)b*C*Mi + (size_t)c*Mi + inner];
    s+=v; q+=v*v;
  }
  rs[tid]=s; rq[tid]=q; __syncthreads();
  for(int k=128;k>0;k>>=1){ if(tid<k){ rs[tid]+=rs[tid+k]; rq[tid]+=rq[tid+k]; } __syncthreads(); }
  if(tid==0){
    float mu=rs[0]/M; float var=rq[0]/M-mu*mu;
    st[c]=mu; st[C+c]=rsqrtf(var+1e-5f);
  }
}

__global__ void k_bnapply(float* __restrict__ h, const float* __restrict__ st,
                          const float* __restrict__ g, const float* __restrict__ bb, int tn){
  int idx=blockIdx.x*256+threadIdx.x;
  if(idx>=B*C*N*tn) return;
  int c=(idx/(N*tn))%C;
  float v=h[idx];
  h[idx]=(v-st[c])*st[C+c]*g[c]+bb[c];
}

__global__ void k_head(const float* __restrict__ skipacc, const float* __restrict__ W1,
  const float* __restrict__ b1, const float* __restrict__ W2, const float* __restrict__ b2,
  float* __restrict__ out){
  int gid=blockIdx.x; int tid=threadIdx.x;  // 512 threads
  int n=gid%N; int b=gid/N;
  __shared__ float s[SKC];
  __shared__ float hid[512];
  if(tid<SKC){
    float v=skipacc[((size_t)b*SKC+tid)*N+n];
    s[tid]=fmaxf(v,0.f);
  }
  __syncthreads();
  {
    float a=b1[tid];
    for(int i=0;i<SKC;i++) a+=s[i]*W1[(size_t)i*512+tid];
    hid[tid]=fmaxf(a,0.f);
  }
  __syncthreads();
  if(tid<T){
    float a=b2[tid];
    for(int j=0;j<512;j++) a+=hid[j]*W2[(size_t)j*T+tid];
    out[((size_t)b*T+tid)*N+n]=a;
  }
}

// ---------------- host-side layer driver ----------------
struct Ctx {
  const float *Wq,*bq,*Wk,*bk,*Wv,*bv,*W1,*b1,*W2,*b2;
  const float *filt_w,*filt_b,*gate_w,*gate_b,*skip_w,*skip_b,*gcn_w,*gcn_b,*bn_g,*bn_b;
  float *pH,*pAlt,*hT,*Pb,*Qb,*skipacc,*bnst;
  const float* Aps[4];
  long long Ast[4];
  hipStream_t stream;
};

template<int TC, int D>
void run_layer(Ctx& c, int l, bool last){
  constexpr int TN=TC-D;
  k_attconv<TC,D><<<B*N,256,0,c.stream>>>(c.pH,
    c.Wq+(size_t)l*C*C, c.bq+(size_t)l*C,
    c.Wk+(size_t)l*C*C, c.bk+(size_t)l*C,
    c.Wv+(size_t)l*C*C, c.bv+(size_t)l*C,
    c.W1+(size_t)l*C*4*C, c.b1+(size_t)l*4*C,
    c.W2+(size_t)l*4*C*C, c.b2+(size_t)l*C,
    c.filt_w+(size_t)l*2*C*C, c.filt_b+(size_t)l*C,
    c.gate_w+(size_t)l*2*C*C, c.gate_b+(size_t)l*C,
    c.hT);
  k_skiplast<<<B*N,256,0,c.stream>>>(c.hT,
    c.skip_w+(size_t)l*C*SKC, c.skip_b+(size_t)l*SKC, c.skipacc, TN, l==0?1:0);
  if(!last){
    k_gcn0<TN><<<B*N,64,0,c.stream>>>(c.hT,
      c.gcn_w+((size_t)l*9*C)*C, c.gcn_b+(size_t)l*C, c.pH, c.pAlt, TC);
    int M=C*TN;
    dim3 sg(DIVUP(N,64), M/64, B);
    for(int s=0;s<4;s++){
      k_spatial<<<sg,256,0,c.stream>>>(c.Aps[s], c.Ast[s], c.hT, c.Pb, M);
      k_gcnacc<TN><<<B*N,64,0,c.stream>>>(c.Pb,
        c.gcn_w+((size_t)l*9*C+(size_t)(1+2*s)*C)*C, c.pAlt);
      k_spatial<<<sg,256,0,c.stream>>>(c.Aps[s], c.Ast[s], c.Pb, c.Qb, M);
      k_gcnacc<TN><<<B*N,64,0,c.stream>>>(c.Qb,
        c.gcn_w+((size_t)l*9*C+(size_t)(2+2*s)*C)*C, c.pAlt);
    }
    k_bnstats<<<C,256,0,c.stream>>>(c.pAlt, c.bnst, TN);
    k_bnapply<<<DIVUP(B*C*N*TN,256),256,0,c.stream>>>(c.pAlt, c.bnst,
      c.bn_g+(size_t)l*C, c.bn_b+(size_t)l*C, TN);
    float* tmp=c.pH; c.pH=c.pAlt; c.pAlt=tmp;
  }
}

} // namespace

extern "C" void kernel_launch(void* const* d_in, const int* in_sizes, int n_in,
                              void* d_out, int out_size, void* d_ws, size_t ws_size,
                              hipStream_t stream){
  (void)in_sizes; (void)n_in;
  const float* x      =(const float*)d_in[0];
  const float* sup0   =(const float*)d_in[1];
  const float* sup1   =(const float*)d_in[2];
  const float* TiD    =(const float*)d_in[3];
  const float* DiW    =(const float*)d_in[4];
  const float* E1     =(const float*)d_in[5];
  const float* E2     =(const float*)d_in[6];
  const float* E3     =(const float*)d_in[7];
  const float* Wx     =(const float*)d_in[8];
  const float* Wd     =(const float*)d_in[9];
  const float* Wxabs  =(const float*)d_in[10];
  const float* start_w=(const float*)d_in[11];
  const float* start_b=(const float*)d_in[12];

  Ctx c;
  c.Wq=(const float*)d_in[13]; c.bq=(const float*)d_in[14];
  c.Wk=(const float*)d_in[15]; c.bk=(const float*)d_in[16];
  c.Wv=(const float*)d_in[17]; c.bv=(const float*)d_in[18];
  c.W1=(const float*)d_in[19]; c.b1=(const float*)d_in[20];
  c.W2=(const float*)d_in[21]; c.b2=(const float*)d_in[22];
  c.filt_w=(const float*)d_in[23]; c.filt_b=(const float*)d_in[24];
  c.gate_w=(const float*)d_in[25]; c.gate_b=(const float*)d_in[26];
  c.skip_w=(const float*)d_in[27]; c.skip_b=(const float*)d_in[28];
  c.gcn_w =(const float*)d_in[29]; c.gcn_b =(const float*)d_in[30];
  c.bn_g  =(const float*)d_in[31]; c.bn_b  =(const float*)d_in[32];
  const float* end1_w =(const float*)d_in[33];
  const float* end1_b =(const float*)d_in[34];
  const float* end2_w =(const float*)d_in[35];
  const float* end2_b =(const float*)d_in[36];
  c.stream=stream;

  // workspace carve (floats, 16B-aligned blocks)
  size_t off=0;
  auto alloc=[&](size_t nf)->float*{
    nf=(nf+3)&~(size_t)3;
    float* p=(float*)((char*)d_ws+off);
    off += nf*sizeof(float);
    return p;
  };
  const size_t HMAX =(size_t)B*C*N*T13;
  const size_t HT12 =(size_t)B*C*N*12;
  float* xf     = alloc((size_t)B*F7*N);
  float* gx1    = alloc((size_t)B*N*E);
  float* gdew   = alloc((size_t)B*N*E);
  float* gst    = alloc(16);
  c.bnst        = alloc(2*C);
  float* adpAD  = alloc((size_t)B*N*N);
  float* adapT  = alloc((size_t)N*N);
  float* s0T    = alloc((size_t)N*N);
  float* s1T    = alloc((size_t)N*N);
  c.pH          = alloc(HMAX);
  c.pAlt        = alloc(HMAX);
  c.hT          = alloc(HT12);
  c.Pb          = alloc(HT12);
  c.Qb          = alloc(HT12);
  c.skipacc     = alloc((size_t)B*SKC*N);
  if(off > ws_size){
    (void)hipMemsetAsync(d_out, 0, (size_t)out_size*sizeof(float), stream);
    return;
  }
  c.Aps[0]=s0T; c.Aps[1]=s1T; c.Aps[2]=adapT; c.Aps[3]=adpAD;
  c.Ast[0]=0; c.Ast[1]=0; c.Ast[2]=0; c.Ast[3]=(long long)N*N;

  // ---- graph generation ----
  k_dft <<<DIVUP(B*F7*N,256),256,0,stream>>>(x, xf);
  k_l2f <<<DIVUP(B*N,256),256,0,stream>>>(xf);
  k_l2n <<<B*F7,256,0,stream>>>(xf);
  k_x1  <<<DIVUP(B*N,256),256,0,stream>>>(x, xf, E3, TiD, DiW, Wx, Wd, gx1);
  k_lnstats<<<B,256,0,stream>>>(gx1, gst);
  k_dew <<<DIVUP(B*N,256),256,0,stream>>>(gx1, gst, Wxabs, gdew);
  k_adp <<<DIVUP(B*N*N,256),256,0,stream>>>(gdew, gx1, adpAD);
  k_topk<<<B*N,256,0,stream>>>(adpAD);
  k_adap<<<N,256,0,stream>>>(E1, E2, adapT);
  k_transNN<<<DIVUP(N*N,256),256,0,stream>>>(sup0, s0T);
  k_transNN<<<DIVUP(N*N,256),256,0,stream>>>(sup1, s1T);

  // ---- trunk ----
  k_start<<<DIVUP(B*C*N*T13,256),256,0,stream>>>(x, start_w, start_b, c.pH);

  run_layer<13,1>(c,0,false);
  run_layer<12,2>(c,1,false);
  run_layer<10,1>(c,2,false);
  run_layer< 9,2>(c,3,false);
  run_layer< 7,1>(c,4,false);
  run_layer< 6,2>(c,5,false);
  run_layer< 4,1>(c,6,false);
  run_layer< 3,2>(c,7,true);

  k_head<<<B*N,512,0,stream>>>(c.skipacc, end1_w, end1_b, end2_w, end2_b, (float*)d_out);
}

// Round 5
// 13994.702 us; speedup vs baseline: 3.2685x; 1.0084x over previous
//
#include <hip/hip_runtime.h>
#include <math.h>

#define DIVUP(a,b) (((a)+(b)-1)/(b))

namespace {

constexpr int B=8, T=12, N=883, CIN=3, C=64, E=10, H=8, HD=8, TOPK=48, L=8;
constexpr int SKC=256, F7=7, T13=13;

__device__ __forceinline__ float geluf(float x){ return 0.5f*x*(1.0f+erff(x*0.7071067811865475f)); }
__device__ __forceinline__ float sigmf(float x){ return 1.0f/(1.0f+expf(-x)); }

// ---------------- graph generation ----------------
__global__ void k_dft(const float* __restrict__ x, float* __restrict__ xf){
  int idx = blockIdx.x*256 + threadIdx.x;
  if(idx >= B*F7*N) return;
  int n = idx % N; int f = (idx/N) % F7; int b = idx/(N*F7);
  float re=0.f, im=0.f;
  for(int t=0;t<T;t++){
    float v = x[((size_t)(b*T+t)*N+n)*CIN];
    float ang = -6.283185307179586f * (float)(f*t) / 12.0f;
    re += v*cosf(ang); im += v*sinf(ang);
  }
  xf[idx] = sqrtf(re*re+im*im);
}

__global__ void k_l2f(float* __restrict__ xf){
  int idx = blockIdx.x*256 + threadIdx.x;
  if(idx >= B*N) return;
  int n = idx % N; int b = idx / N;
  float s=0.f;
  for(int f=0;f<F7;f++){ float v=xf[((size_t)b*F7+f)*N+n]; s+=v*v; }
  float inv = 1.0f/fmaxf(sqrtf(s), 1e-12f);
  for(int f=0;f<F7;f++) xf[((size_t)b*F7+f)*N+n] *= inv;
}

__global__ void k_l2n(float* __restrict__ xf){
  int bf = blockIdx.x; int tid = threadIdx.x;
  __shared__ float red[256];
  size_t base = (size_t)bf*N;
  float s=0.f;
  for(int i=tid;i<N;i+=256){ float v=xf[base+i]; s+=v*v; }
  red[tid]=s; __syncthreads();
  for(int k=128;k>0;k>>=1){ if(tid<k) red[tid]+=red[tid+k]; __syncthreads(); }
  float inv = 1.0f/fmaxf(sqrtf(red[0]), 1e-12f);
  __syncthreads();
  for(int i=tid;i<N;i+=256) xf[base+i]*=inv;
}

__global__ void k_x1(const float* __restrict__ x, const float* __restrict__ xf,
                     const float* __restrict__ E3, const float* __restrict__ TiD,
                     const float* __restrict__ DiW, const float* __restrict__ Wx,
                     const float* __restrict__ Wd, float* __restrict__ x1){
  int idx = blockIdx.x*256+threadIdx.x;
  if(idx>=B*N) return;
  int n=idx%N, b=idx/N;
  float xc[40];
  for(int d=0;d<E;d++){
    float a=0.f;
    for(int f=0;f<F7;f++) a += xf[((size_t)b*F7+f)*N+n]*Wx[f*E+d];
    xc[d]=a;
  }
  for(int d=0;d<E;d++) xc[10+d]=E3[n*E+d];
  int ti = (int)(x[((size_t)(b*T+(T-1))*N+n)*CIN+1]*288.0f);
  int dw = (int)(x[((size_t)(b*T+(T-1))*N+n)*CIN+2]);
  for(int d=0;d<E;d++) xc[20+d]=TiD[ti*E+d];
  for(int d=0;d<E;d++) xc[30+d]=DiW[dw*E+d];
  for(int e=0;e<E;e++){
    float a=0.f;
    for(int f=0;f<40;f++) a += xc[f]*Wd[((size_t)n*40+f)*E+e];
    x1[(size_t)idx*E+e]=fmaxf(a,0.f);
  }
}

__global__ void k_lnstats(const float* __restrict__ x1, float* __restrict__ st){
  int b=blockIdx.x, tid=threadIdx.x;
  __shared__ float rs[256], rq[256];
  const int M=N*E;
  float s=0.f,q=0.f;
  for(int i=tid;i<M;i+=256){ float v=x1[(size_t)b*M+i]; s+=v; q+=v*v; }
  rs[tid]=s; rq[tid]=q; __syncthreads();
  for(int k=128;k>0;k>>=1){ if(tid<k){ rs[tid]+=rs[tid+k]; rq[tid]+=rq[tid+k]; } __syncthreads(); }
  if(tid==0){ float mu=rs[0]/M; float var=rq[0]/M-mu*mu; st[b*2]=mu; st[b*2+1]=var; }
}

__global__ void k_dew(const float* __restrict__ x1, const float* __restrict__ st,
                      const float* __restrict__ Wxabs, float* __restrict__ dew){
  int idx=blockIdx.x*256+threadIdx.x;
  if(idx>=B*N) return;
  int b=idx/N;
  float mu=st[b*2], var=st[b*2+1];
  float rs=rsqrtf(var+1e-8f);
  float xk[E];
  for(int e=0;e<E;e++) xk[e]=(x1[(size_t)idx*E+e]-mu)*rs;
  for(int k=0;k<E;k++){
    float a=0.f;
    for(int e=0;e<E;e++) a+=xk[e]*Wxabs[e*E+k];
    dew[(size_t)idx*E+k]=a;
  }
}

__global__ void k_adp(const float* __restrict__ dew, const float* __restrict__ x1,
                      float* __restrict__ adp){
  size_t idx=(size_t)blockIdx.x*256+threadIdx.x;
  if(idx>=(size_t)B*N*N) return;
  int m=(int)(idx%N); int n=(int)((idx/N)%N); int b=(int)(idx/((size_t)N*N));
  const float* dr=dew+((size_t)b*N+n)*E;
  const float* xr=x1+((size_t)b*N+m)*E;
  float a=0.f;
  for(int k=0;k<E;k++) a+=dr[k]*xr[k];
  adp[idx]=fmaxf(a,0.f);
}

__global__ void k_topk(float* __restrict__ adp){
  int row=blockIdx.x, tid=threadIdx.x;
  __shared__ float orig[N];
  __shared__ float work[N];
  __shared__ float rv[256];
  __shared__ int   ri[256];
  for(int i=tid;i<N;i+=256){ float v=adp[(size_t)row*N+i]; orig[i]=v; work[i]=v; }
  __syncthreads();
  for(int k=0;k<TOPK;k++){
    float bv=-1.f; int bi=N;
    for(int i=tid;i<N;i+=256){ float v=work[i]; if(v>bv){bv=v;bi=i;} }
    rv[tid]=bv; ri[tid]=bi; __syncthreads();
    for(int s=128;s>0;s>>=1){
      if(tid<s){
        if(rv[tid+s]>rv[tid] || (rv[tid+s]==rv[tid] && ri[tid+s]<ri[tid])){
          rv[tid]=rv[tid+s]; ri[tid]=ri[tid+s];
        }
      }
      __syncthreads();
    }
    if(tid==0) work[ri[0]] = -2.f;
    __syncthreads();
  }
  float lm=0.f;
  for(int i=tid;i<N;i+=256){ float p=(work[i]<-1.f)?orig[i]:0.f; lm=fmaxf(lm,p); }
  rv[tid]=lm; __syncthreads();
  for(int s=128;s>0;s>>=1){ if(tid<s) rv[tid]=fmaxf(rv[tid],rv[tid+s]); __syncthreads(); }
  float m=rv[0]; __syncthreads();
  float ls=0.f;
  for(int i=tid;i<N;i+=256){ float p=(work[i]<-1.f)?orig[i]:0.f; ls+=expf(p-m); }
  rv[tid]=ls; __syncthreads();
  for(int s=128;s>0;s>>=1){ if(tid<s) rv[tid]+=rv[tid+s]; __syncthreads(); }
  float invZ=1.0f/rv[0]; __syncthreads();
  for(int i=tid;i<N;i+=256){ float p=(work[i]<-1.f)?orig[i]:0.f; adp[(size_t)row*N+i]=expf(p-m)*invZ; }
}

__global__ void k_adap(const float* __restrict__ E1, const float* __restrict__ E2,
                       float* __restrict__ adapT){
  int v=blockIdx.x, tid=threadIdx.x;
  __shared__ float rowv[N];
  __shared__ float rv[256];
  float e1[E];
  for(int e=0;e<E;e++) e1[e]=E1[v*E+e];
  for(int j=tid;j<N;j+=256){
    float s=0.f;
    for(int e=0;e<E;e++) s+=e1[e]*E2[j*E+e];
    rowv[j]=fmaxf(s,0.f);
  }
  __syncthreads();
  float lm=-1e30f;
  for(int j=tid;j<N;j+=256) lm=fmaxf(lm,rowv[j]);
  rv[tid]=lm; __syncthreads();
  for(int s=128;s>0;s>>=1){ if(tid<s) rv[tid]=fmaxf(rv[tid],rv[tid+s]); __syncthreads(); }
  float m=rv[0]; __syncthreads();
  float ls=0.f;
  for(int j=tid;j<N;j+=256) ls+=expf(rowv[j]-m);
  rv[tid]=ls; __syncthreads();
  for(int s=128;s>0;s>>=1){ if(tid<s) rv[tid]+=rv[tid+s]; __syncthreads(); }
  float invZ=1.0f/rv[0];
  for(int j=tid;j<N;j+=256) adapT[(size_t)j*N+v]=expf(rowv[j]-m)*invZ;
}

__global__ void k_transNN(const float* __restrict__ src, float* __restrict__ dst){
  size_t idx=(size_t)blockIdx.x*256+threadIdx.x;
  if(idx>=(size_t)N*N) return;
  int j=(int)(idx%N), i=(int)(idx/N);
  dst[(size_t)j*N+i]=src[idx];
}

__global__ void k_zero(float* __restrict__ p, int n){
  int idx=blockIdx.x*256+threadIdx.x;
  if(idx<n) p[idx]=0.f;
}

// ---------------- trunk ----------------
__global__ void k_start(const float* __restrict__ x, const float* __restrict__ sw,
                        const float* __restrict__ sb, float* __restrict__ h){
  int idx=blockIdx.x*256+threadIdx.x;
  if(idx>=B*C*N*T13) return;
  int t=idx%T13; int n=(idx/T13)%N; int o=(idx/(T13*N))%C; int b=idx/(T13*N*C);
  float a=sb[o];
  if(t>0){
    size_t xb=((size_t)(b*T+(t-1))*N+n)*CIN;
    for(int i=0;i<CIN;i++) a += sw[i*C+o]*x[xb+i];
  }
  h[idx]=a;
}

// Fused per-(b,n): QKV+gelu+causal attn+FFN+residual+gated dilated conv+skip.
// Writes hT (conv output, [b][n][c][tt]) and skipacc += (last column skip proj).
template<int TC, int D>
__global__ __launch_bounds__(256) void k_attconv(const float* __restrict__ hin,
  const float* __restrict__ Wq, const float* __restrict__ bq,
  const float* __restrict__ Wk, const float* __restrict__ bk,
  const float* __restrict__ Wv, const float* __restrict__ bv,
  const float* __restrict__ W1, const float* __restrict__ b1,
  const float* __restrict__ W2, const float* __restrict__ b2,
  const float* __restrict__ fw, const float* __restrict__ fb,
  const float* __restrict__ gw, const float* __restrict__ gb,
  const float* __restrict__ skw, const float* __restrict__ skb,
  float* __restrict__ hT, float* __restrict__ skipacc){
  constexpr int TN = TC - D;
  int bn=blockIdx.x; int tid=threadIdx.x;
  int n=bn%N, b=bn/N;
  __shared__ float sxa [T13*C];
  __shared__ float sq  [T13*C];
  __shared__ float sk  [T13*C];
  __shared__ float sv  [T13*C];
  __shared__ float so  [T13*C];
  __shared__ float shid[T13*4*C];

  // load layer input slice
  for(int idx=tid; idx<TC*C; idx+=256){
    int c=idx/TC, t=idx%TC;
    sxa[t*C+c]=hin[(((size_t)b*C+c)*N+n)*TC+t];
  }
  __syncthreads();

  // QKV projection + gelu: 192 threads, acc[TC] register reuse
  if(tid<192){
    int m=tid>>6, o=tid&63;
    const float* Wm=(m==0)?Wq:((m==1)?Wk:Wv);
    const float* bm=(m==0)?bq:((m==1)?bk:bv);
    float acc[TC];
    #pragma unroll
    for(int t=0;t<TC;t++) acc[t]=bm[o];
    for(int i=0;i<C;i++){
      float w=Wm[i*C+o];
      #pragma unroll
      for(int t=0;t<TC;t++) acc[t]+=w*sxa[t*C+i];
    }
    float* dst=(m==0)?sq:((m==1)?sk:sv);
    #pragma unroll
    for(int t=0;t<TC;t++) dst[t*C+o]=geluf(acc[t]);
  }
  __syncthreads();

  // causal attention: thread per (head,t)
  if(tid<H*TC){
    int hh=tid/TC, t=tid%TC;
    const float* qr=&sq[t*C+hh*HD];
    float att[TC];
    float m=-1e30f;
    #pragma unroll
    for(int s=0;s<TC;s++){
      float a=0.f;
      #pragma unroll
      for(int d=0;d<HD;d++) a+=qr[d]*sk[s*C+hh*HD+d];
      a*=0.3535533905932738f;
      a=(s<=t)?a:-1e30f;
      att[s]=a; m=fmaxf(m,a);
    }
    float Z=0.f;
    #pragma unroll
    for(int s=0;s<TC;s++){ float e=expf(att[s]-m); att[s]=e; Z+=e; }
    float invZ=1.0f/Z;
    #pragma unroll
    for(int d=0;d<HD;d++){
      float o=0.f;
      #pragma unroll
      for(int s=0;s<TC;s++) o+=att[s]*sv[s*C+hh*HD+d];
      so[t*C+hh*HD+d]=o*invZ;
    }
  }
  __syncthreads();

  // FFN1: 256 outputs, acc[TC] register reuse
  {
    int j=tid;
    float acc[TC];
    #pragma unroll
    for(int t=0;t<TC;t++) acc[t]=b1[j];
    for(int i=0;i<C;i++){
      float w=W1[(size_t)i*4*C+j];
      #pragma unroll
      for(int t=0;t<TC;t++) acc[t]+=w*so[t*C+i];
    }
    #pragma unroll
    for(int t=0;t<TC;t++) shid[t*4*C+j]=geluf(acc[t]);
  }
  __syncthreads();

  // FFN2: K=256 split over 4 parts of 64
  {
    int o=tid&63, part=tid>>6;
    float acc[TC];
    #pragma unroll
    for(int t=0;t<TC;t++) acc[t]=(part==0)?b2[o]:0.f;
    for(int jj=0;jj<64;jj++){
      int j=part*64+jj;
      float w=W2[(size_t)j*C+o];
      #pragma unroll
      for(int t=0;t<TC;t++) acc[t]+=w*shid[t*4*C+j];
    }
    if(part==1){
      #pragma unroll
      for(int t=0;t<TC;t++) sq[t*C+o]=acc[t];
    }else if(part==2){
      #pragma unroll
      for(int t=0;t<TC;t++) sk[t*C+o]=acc[t];
    }else if(part==3){
      #pragma unroll
      for(int t=0;t<TC;t++) sv[t*C+o]=acc[t];
    }
    __syncthreads();
    if(part==0){
      #pragma unroll
      for(int t=0;t<TC;t++){
        float fin=acc[t]+sq[t*C+o]+sk[t*C+o]+sv[t*C+o]+sxa[t*C+o];
        shid[t*C+o]=fin;   // reuse shid[0..TC*C) as conv input
      }
    }
  }
  __syncthreads();

  // gated dilated conv on shid[0..TC*C)
  if(tid<128){
    int c=tid&63, m=tid>>6;
    const float* base=m?gw:fw;
    float acc[TN];
    #pragma unroll
    for(int tt=0;tt<TN;tt++) acc[tt]=0.f;
    for(int i=0;i<C;i++){
      float w0=base[i*C+c];
      float w1=base[C*C+i*C+c];
      #pragma unroll
      for(int tt=0;tt<TN;tt++) acc[tt]+=w0*shid[tt*C+i]+w1*shid[(tt+D)*C+i];
    }
    float bi=m?gb[c]:fb[c];
    if(m==0){
      #pragma unroll
      for(int tt=0;tt<TN;tt++) sq[tt*C+c]=tanhf(acc[tt]+bi);
    }else{
      #pragma unroll
      for(int tt=0;tt<TN;tt++) sk[tt*C+c]=sigmf(acc[tt]+bi);
    }
  }
  __syncthreads();

  // stage last-column conv output for skip projection
  if(tid<C) so[tid]=sq[(TN-1)*C+tid]*sk[(TN-1)*C+tid];
  __syncthreads();

  // skip projection: 256 outputs, K=64
  {
    float a=skb[tid];
    for(int i=0;i<C;i++) a+=so[i]*skw[i*SKC+tid];
    skipacc[((size_t)b*SKC+tid)*N+n]+=a;
  }

  // coalesced hT write: [b][n][c][tt]
  size_t obase=(size_t)bn*C*TN;
  for(int idx=tid; idx<C*TN; idx+=256){
    int c=idx/TN, tt=idx%TN;
    hT[obase+idx]=sq[tt*C+c]*sk[tt*C+c];
  }
}

// ---- batched spatial: all 4 supports in one launch ----
// Y[(s*B+b)] = A_s' @ X[...]; As layout TRANSPOSED in LDS for float4 reads.
__global__ __launch_bounds__(256) void k_spatial4(
    const float* __restrict__ A0, const float* __restrict__ A1,
    const float* __restrict__ A2, const float* __restrict__ A3,
    const float* __restrict__ X, float* __restrict__ Y,
    int M, int nMB, int xPerS){
  __shared__ float As[64][68];   // [k][row]
  __shared__ float Bs[64][68];   // [k][col]
  int b=blockIdx.z;
  int sidx=blockIdx.y/nMB, mb=blockIdx.y%nMB;
  const float* Ab = (sidx==0)?A0 : (sidx==1)?A1 : (sidx==2)?A2 : (A3+(size_t)b*N*N);
  const float* Xb = X + (size_t)(xPerS ? (sidx*B+b) : b)*N*M;
  float* Yb = Y + (size_t)(sidx*B+b)*N*M;
  int tid=threadIdx.x;
  int lrow=tid>>6, lcol=tid&63;
  int tx=tid&15, ty=tid>>4;
  int rowBase=blockIdx.x*64, colBase=mb*64;
  float acc[4][4];
  #pragma unroll
  for(int i=0;i<4;i++){
    #pragma unroll
    for(int j=0;j<4;j++) acc[i][j]=0.f;
  }
  for(int k0=0;k0<N;k0+=64){
    #pragma unroll
    for(int e=0;e<16;e++){
      int row=lrow+e*4;
      int ar=rowBase+row, ak=k0+lcol;
      As[lcol][row]=(ar<N&&ak<N)?Ab[(size_t)ar*N+ak]:0.f;   // transposed store
      int bk=k0+row;
      Bs[row][lcol]=(bk<N)?Xb[(size_t)bk*M+colBase+lcol]:0.f;
    }
    __syncthreads();
    #pragma unroll 4
    for(int kk=0;kk<64;kk++){
      float4 bv=*(const float4*)&Bs[kk][tx*4];
      float4 av=*(const float4*)&As[kk][ty*4];
      acc[0][0]+=av.x*bv.x; acc[0][1]+=av.x*bv.y; acc[0][2]+=av.x*bv.z; acc[0][3]+=av.x*bv.w;
      acc[1][0]+=av.y*bv.x; acc[1][1]+=av.y*bv.y; acc[1][2]+=av.y*bv.z; acc[1][3]+=av.y*bv.w;
      acc[2][0]+=av.z*bv.x; acc[2][1]+=av.z*bv.y; acc[2][2]+=av.z*bv.z; acc[2][3]+=av.z*bv.w;
      acc[3][0]+=av.w*bv.x; acc[3][1]+=av.w*bv.y; acc[3][2]+=av.w*bv.z; acc[3][3]+=av.w*bv.w;
    }
    __syncthreads();
  }
  #pragma unroll
  for(int i=0;i<4;i++){
    int r=rowBase+ty*4+i;
    if(r<N){
      float4 v; v.x=acc[i][0]; v.y=acc[i][1]; v.z=acc[i][2]; v.w=acc[i][3];
      *(float4*)&Yb[(size_t)r*M+colBase+tx*4]=v;
    }
  }
}

// fused GCN projection: acc = gcn_b + residual + sum_{j=0..8} slice_j @ W_j
// slices: j=0 hT, j=1+2s P[s], j=2+2s Q[s]; per (b,n) block, 256 threads.
template<int TN>
__global__ __launch_bounds__(256) void k_gcnproj(const float* __restrict__ hT,
    const float* __restrict__ P, const float* __restrict__ Q,
    const float* __restrict__ Wg, const float* __restrict__ gb,
    const float* __restrict__ res, float* __restrict__ acc, int Tc){
  constexpr int SL=C*TN;
  int bn=blockIdx.x; int tid=threadIdx.x;
  int n=bn%N, b=bn/N;
  __shared__ float sx[9*SL];
  {
    const float* s0=hT+(size_t)bn*SL;
    for(int i=tid;i<SL;i+=256) sx[i]=s0[i];
    for(int s=0;s<4;s++){
      const float* ps=P+((size_t)s*B*N+bn)*SL;
      const float* qs=Q+((size_t)s*B*N+bn)*SL;
      for(int i=tid;i<SL;i+=256){
        sx[(1+2*s)*SL+i]=ps[i];
        sx[(2+2*s)*SL+i]=qs[i];
      }
    }
  }
  __syncthreads();
  int o=tid&63, part=tid>>6;
  float a[TN];
  #pragma unroll
  for(int tt=0;tt<TN;tt++) a[tt]=0.f;
  for(int j=0;j<9;j++){
    const float* Wj=Wg+((size_t)j*C)*C;
    const float* xj=&sx[j*SL];
    for(int ii=0;ii<16;ii++){
      int i=part*16+ii;
      float w=Wj[i*C+o];
      #pragma unroll
      for(int tt=0;tt<TN;tt++) a[tt]+=w*xj[i*TN+tt];
    }
  }
  __syncthreads();
  float* red=sx;  // reuse LDS
  #pragma unroll
  for(int tt=0;tt<TN;tt++) red[(part*64+o)*TN+tt]=a[tt];
  __syncthreads();
  if(part==0){
    float g=gb[o];
    size_t rb=(((size_t)b*C+o)*N+n)*Tc+(Tc-TN);
    size_t ob=(((size_t)b*C+o)*N+n)*TN;
    #pragma unroll
    for(int tt=0;tt<TN;tt++){
      float v=red[o*TN+tt]+red[(64+o)*TN+tt]+red[(128+o)*TN+tt]+red[(192+o)*TN+tt];
      acc[ob+tt]=v+g+res[rb+tt];
    }
  }
}

// ---- fallback (sequential) spatial path, verified in round 4 ----
__global__ __launch_bounds__(256) void k_spatial(
    const float* __restrict__ A, long long aStride,
    const float* __restrict__ X, float* __restrict__ Y, int M){
  __shared__ float As[64][68];
  __shared__ float Bs[64][68];
  int b=blockIdx.z;
  const float* Ab=A+(size_t)b*aStride;
  const float* Xb=X+(size_t)b*N*M;
  float* Yb=Y+(size_t)b*N*M;
  int tid=threadIdx.x;
  int lrow=tid>>6, lcol=tid&63;
  int tx=tid&15, ty=tid>>4;
  int rowBase=blockIdx.x*64, colBase=blockIdx.y*64;
  float acc[4][4];
  #pragma unroll
  for(int i=0;i<4;i++){
    #pragma unroll
    for(int j=0;j<4;j++) acc[i][j]=0.f;
  }
  for(int k0=0;k0<N;k0+=64){
    #pragma unroll
    for(int e=0;e<16;e++){
      int row=lrow+e*4;
      int ar=rowBase+row, ak=k0+lcol;
      As[row][lcol]=(ar<N&&ak<N)?Ab[(size_t)ar*N+ak]:0.f;
      int bk=k0+row;
      Bs[row][lcol]=(bk<N)?Xb[(size_t)bk*M+colBase+lcol]:0.f;
    }
    __syncthreads();
    #pragma unroll 4
    for(int kk=0;kk<64;kk++){
      float4 bv=*(const float4*)&Bs[kk][tx*4];
      float a0=As[ty*4+0][kk], a1=As[ty*4+1][kk], a2=As[ty*4+2][kk], a3=As[ty*4+3][kk];
      acc[0][0]+=a0*bv.x; acc[0][1]+=a0*bv.y; acc[0][2]+=a0*bv.z; acc[0][3]+=a0*bv.w;
      acc[1][0]+=a1*bv.x; acc[1][1]+=a1*bv.y; acc[1][2]+=a1*bv.z; acc[1][3]+=a1*bv.w;
      acc[2][0]+=a2*bv.x; acc[2][1]+=a2*bv.y; acc[2][2]+=a2*bv.z; acc[2][3]+=a2*bv.w;
      acc[3][0]+=a3*bv.x; acc[3][1]+=a3*bv.y; acc[3][2]+=a3*bv.z; acc[3][3]+=a3*bv.w;
    }
    __syncthreads();
  }
  #pragma unroll
  for(int i=0;i<4;i++){
    int r=rowBase+ty*4+i;
    if(r<N){
      float4 v; v.x=acc[i][0]; v.y=acc[i][1]; v.z=acc[i][2]; v.w=acc[i][3];
      *(float4*)&Yb[(size_t)r*M+colBase+tx*4]=v;
    }
  }
}

template<int TN>
__global__ void k_gcn0(const float* __restrict__ hT, const float* __restrict__ Wc,
                       const float* __restrict__ gb, const float* __restrict__ res,
                       float* __restrict__ acc, int Tc){
  int bn=blockIdx.x; int o=threadIdx.x;
  int n=bn%N, b=bn/N;
  __shared__ float sx[C*TN];
  size_t base=(size_t)bn*C*TN;
  for(int idx=o; idx<C*TN; idx+=64) sx[idx]=hT[base+idx];
  __syncthreads();
  float a[TN];
  #pragma unroll
  for(int tt=0;tt<TN;tt++) a[tt]=0.f;
  for(int i=0;i<C;i++){
    float w=Wc[i*C+o];
    #pragma unroll
    for(int tt=0;tt<TN;tt++) a[tt]+=w*sx[i*TN+tt];
  }
  size_t rbase=(((size_t)b*C+o)*N+n)*Tc+(Tc-TN);
  size_t obase=(((size_t)b*C+o)*N+n)*TN;
  float g=gb[o];
  #pragma unroll
  for(int tt=0;tt<TN;tt++) acc[obase+tt]=a[tt]+g+res[rbase+tt];
}

template<int TN>
__global__ void k_gcnacc(const float* __restrict__ xT, const float* __restrict__ Wc,
                         float* __restrict__ acc){
  int bn=blockIdx.x; int o=threadIdx.x;
  __shared__ float sx[C*TN];
  size_t base=(size_t)bn*C*TN;
  for(int idx=o; idx<C*TN; idx+=64) sx[idx]=xT[base+idx];
  __syncthreads();
  float a[TN];
  #pragma unroll
  for(int tt=0;tt<TN;tt++) a[tt]=0.f;
  for(int i=0;i<C;i++){
    float w=Wc[i*C+o];
    #pragma unroll
    for(int tt=0;tt<TN;tt++) a[tt]+=w*sx[i*TN+tt];
  }
  int n=bn%N, b=bn/N;
  size_t obase=(((size_t)b*C+o)*N+n)*TN;
  #pragma unroll
  for(int tt=0;tt<TN;tt++) acc[obase+tt]+=a[tt];
}

__global__ void k_bnstats(const float* __restrict__ h, float* __restrict__ st, int tn){
  int c=blockIdx.x, tid=threadIdx.x;
  __shared__ float rs[256], rq[256];
  const int Mi=N*tn;
  const int M=B*Mi;
  float s=0.f,q=0.f;
  for(int idx=tid; idx<M; idx+=256){
    int b=idx/Mi; int inner=idx%Mi;
    float v=h[(size_t)b*C*Mi + (size_t)c*Mi + inner];
    s+=v; q+=v*v;
  }
  rs[tid]=s; rq[tid]=q; __syncthreads();
  for(int k=128;k>0;k>>=1){ if(tid<k){ rs[tid]+=rs[tid+k]; rq[tid]+=rq[tid+k]; } __syncthreads(); }
  if(tid==0){
    float mu=rs[0]/M; float var=rq[0]/M-mu*mu;
    st[c]=mu; st[C+c]=rsqrtf(var+1e-5f);
  }
}

__global__ void k_bnapply(float* __restrict__ h, const float* __restrict__ st,
                          const float* __restrict__ g, const float* __restrict__ bb, int tn){
  int idx=blockIdx.x*256+threadIdx.x;
  if(idx>=B*C*N*tn) return;
  int c=(idx/(N*tn))%C;
  float v=h[idx];
  h[idx]=(v-st[c])*st[C+c]*g[c]+bb[c];
}

__global__ void k_head(const float* __restrict__ skipacc, const float* __restrict__ W1,
  const float* __restrict__ b1, const float* __restrict__ W2, const float* __restrict__ b2,
  float* __restrict__ out){
  int gid=blockIdx.x; int tid=threadIdx.x;  // 512 threads
  int n=gid%N; int b=gid/N;
  __shared__ float s[SKC];
  __shared__ float hid[512];
  if(tid<SKC){
    float v=skipacc[((size_t)b*SKC+tid)*N+n];
    s[tid]=fmaxf(v,0.f);
  }
  __syncthreads();
  {
    float a=b1[tid];
    for(int i=0;i<SKC;i++) a+=s[i]*W1[(size_t)i*512+tid];
    hid[tid]=fmaxf(a,0.f);
  }
  __syncthreads();
  if(tid<T){
    float a=b2[tid];
    for(int j=0;j<512;j++) a+=hid[j]*W2[(size_t)j*T+tid];
    out[((size_t)b*T+tid)*N+n]=a;
  }
}

// ---------------- host-side layer driver ----------------
struct Ctx {
  const float *Wq,*bq,*Wk,*bk,*Wv,*bv,*W1,*b1,*W2,*b2;
  const float *filt_w,*filt_b,*gate_w,*gate_b,*skip_w,*skip_b,*gcn_w,*gcn_b,*bn_g,*bn_b;
  float *pH,*pAlt,*hT,*Pb,*Qb,*skipacc,*bnst;
  const float* Aps[4];
  long long Ast[4];
  bool batched;
  hipStream_t stream;
};

template<int TC, int D>
void run_layer(Ctx& c, int l, bool last){
  constexpr int TN=TC-D;
  k_attconv<TC,D><<<B*N,256,0,c.stream>>>(c.pH,
    c.Wq+(size_t)l*C*C, c.bq+(size_t)l*C,
    c.Wk+(size_t)l*C*C, c.bk+(size_t)l*C,
    c.Wv+(size_t)l*C*C, c.bv+(size_t)l*C,
    c.W1+(size_t)l*C*4*C, c.b1+(size_t)l*4*C,
    c.W2+(size_t)l*4*C*C, c.b2+(size_t)l*C,
    c.filt_w+(size_t)l*2*C*C, c.filt_b+(size_t)l*C,
    c.gate_w+(size_t)l*2*C*C, c.gate_b+(size_t)l*C,
    c.skip_w+(size_t)l*C*SKC, c.skip_b+(size_t)l*SKC,
    c.hT, c.skipacc);
  if(last) return;
  int M=C*TN;
  if(c.batched){
    int nMB=M/64;
    dim3 sg(DIVUP(N,64), 4*nMB, B);
    k_spatial4<<<sg,256,0,c.stream>>>(c.Aps[0],c.Aps[1],c.Aps[2],c.Aps[3],
        c.hT, c.Pb, M, nMB, 0);
    k_spatial4<<<sg,256,0,c.stream>>>(c.Aps[0],c.Aps[1],c.Aps[2],c.Aps[3],
        c.Pb, c.Qb, M, nMB, 1);
    k_gcnproj<TN><<<B*N,256,0,c.stream>>>(c.hT, c.Pb, c.Qb,
        c.gcn_w+(size_t)l*9*C*C, c.gcn_b+(size_t)l*C, c.pH, c.pAlt, TC);
  }else{
    k_gcn0<TN><<<B*N,64,0,c.stream>>>(c.hT,
      c.gcn_w+((size_t)l*9*C)*C, c.gcn_b+(size_t)l*C, c.pH, c.pAlt, TC);
    dim3 sg(DIVUP(N,64), M/64, B);
    for(int s=0;s<4;s++){
      k_spatial<<<sg,256,0,c.stream>>>(c.Aps[s], c.Ast[s], c.hT, c.Pb, M);
      k_gcnacc<TN><<<B*N,64,0,c.stream>>>(c.Pb,
        c.gcn_w+((size_t)l*9*C+(size_t)(1+2*s)*C)*C, c.pAlt);
      k_spatial<<<sg,256,0,c.stream>>>(c.Aps[s], c.Ast[s], c.Pb, c.Qb, M);
      k_gcnacc<TN><<<B*N,64,0,c.stream>>>(c.Qb,
        c.gcn_w+((size_t)l*9*C+(size_t)(2+2*s)*C)*C, c.pAlt);
    }
  }
  k_bnstats<<<C,256,0,c.stream>>>(c.pAlt, c.bnst, TN);
  k_bnapply<<<DIVUP(B*C*N*TN,256),256,0,c.stream>>>(c.pAlt, c.bnst,
    c.bn_g+(size_t)l*C, c.bn_b+(size_t)l*C, TN);
  float* tmp=c.pH; c.pH=c.pAlt; c.pAlt=tmp;
}

} // namespace

extern "C" void kernel_launch(void* const* d_in, const int* in_sizes, int n_in,
                              void* d_out, int out_size, void* d_ws, size_t ws_size,
                              hipStream_t stream){
  (void)in_sizes; (void)n_in;
  const float* x      =(const float*)d_in[0];
  const float* sup0   =(const float*)d_in[1];
  const float* sup1   =(const float*)d_in[2];
  const float* TiD    =(const float*)d_in[3];
  const float* DiW    =(const float*)d_in[4];
  const float* E1     =(const float*)d_in[5];
  const float* E2     =(const float*)d_in[6];
  const float* E3     =(const float*)d_in[7];
  const float* Wx     =(const float*)d_in[8];
  const float* Wd     =(const float*)d_in[9];
  const float* Wxabs  =(const float*)d_in[10];
  const float* start_w=(const float*)d_in[11];
  const float* start_b=(const float*)d_in[12];

  Ctx c;
  c.Wq=(const float*)d_in[13]; c.bq=(const float*)d_in[14];
  c.Wk=(const float*)d_in[15]; c.bk=(const float*)d_in[16];
  c.Wv=(const float*)d_in[17]; c.bv=(const float*)d_in[18];
  c.W1=(const float*)d_in[19]; c.b1=(const float*)d_in[20];
  c.W2=(const float*)d_in[21]; c.b2=(const float*)d_in[22];
  c.filt_w=(const float*)d_in[23]; c.filt_b=(const float*)d_in[24];
  c.gate_w=(const float*)d_in[25]; c.gate_b=(const float*)d_in[26];
  c.skip_w=(const float*)d_in[27]; c.skip_b=(const float*)d_in[28];
  c.gcn_w =(const float*)d_in[29]; c.gcn_b =(const float*)d_in[30];
  c.bn_g  =(const float*)d_in[31]; c.bn_b  =(const float*)d_in[32];
  const float* end1_w =(const float*)d_in[33];
  const float* end1_b =(const float*)d_in[34];
  const float* end2_w =(const float*)d_in[35];
  const float* end2_b =(const float*)d_in[36];
  c.stream=stream;

  // workspace carve (floats, 16B-aligned blocks)
  size_t off=0;
  auto alloc=[&](size_t nf)->float*{
    nf=(nf+3)&~(size_t)3;
    float* p=(float*)((char*)d_ws+off);
    off += nf*sizeof(float);
    return p;
  };
  const size_t HMAX =(size_t)B*C*N*T13;
  const size_t HT12 =(size_t)B*C*N*12;
  // base need (excluding P/Q): computed by doing base allocs first
  float* xf     = alloc((size_t)B*F7*N);
  float* gx1    = alloc((size_t)B*N*E);
  float* gdew   = alloc((size_t)B*N*E);
  float* gst    = alloc(16);
  c.bnst        = alloc(2*C);
  float* adpAD  = alloc((size_t)B*N*N);
  float* adapT  = alloc((size_t)N*N);
  float* s0T    = alloc((size_t)N*N);
  float* s1T    = alloc((size_t)N*N);
  c.pH          = alloc(HMAX);
  c.pAlt        = alloc(HMAX);
  c.hT          = alloc(HT12);
  c.skipacc     = alloc((size_t)B*SKC*N);
  size_t base_bytes = off;
  size_t batched_bytes = base_bytes + 8*((HT12+3)&~(size_t)3)*sizeof(float);
  size_t seq_bytes     = base_bytes + 2*((HT12+3)&~(size_t)3)*sizeof(float);
  if(ws_size >= batched_bytes){
    c.batched = true;
    c.Pb = alloc(4*HT12);
    c.Qb = alloc(4*HT12);
  }else if(ws_size >= seq_bytes){
    c.batched = false;
    c.Pb = alloc(HT12);
    c.Qb = alloc(HT12);
  }else{
    k_zero<<<DIVUP(out_size,256),256,0,stream>>>((float*)d_out, out_size);
    return;
  }
  c.Aps[0]=s0T; c.Aps[1]=s1T; c.Aps[2]=adapT; c.Aps[3]=adpAD;
  c.Ast[0]=0; c.Ast[1]=0; c.Ast[2]=0; c.Ast[3]=(long long)N*N;

  // ---- graph generation ----
  k_dft <<<DIVUP(B*F7*N,256),256,0,stream>>>(x, xf);
  k_l2f <<<DIVUP(B*N,256),256,0,stream>>>(xf);
  k_l2n <<<B*F7,256,0,stream>>>(xf);
  k_x1  <<<DIVUP(B*N,256),256,0,stream>>>(x, xf, E3, TiD, DiW, Wx, Wd, gx1);
  k_lnstats<<<B,256,0,stream>>>(gx1, gst);
  k_dew <<<DIVUP(B*N,256),256,0,stream>>>(gx1, gst, Wxabs, gdew);
  k_adp <<<DIVUP(B*N*N,256),256,0,stream>>>(gdew, gx1, adpAD);
  k_topk<<<B*N,256,0,stream>>>(adpAD);
  k_adap<<<N,256,0,stream>>>(E1, E2, adapT);
  k_transNN<<<DIVUP(N*N,256),256,0,stream>>>(sup0, s0T);
  k_transNN<<<DIVUP(N*N,256),256,0,stream>>>(sup1, s1T);

  // ---- trunk ----
  k_zero<<<DIVUP(B*SKC*N,256),256,0,stream>>>(c.skipacc, B*SKC*N);
  k_start<<<DIVUP(B*C*N*T13,256),256,0,stream>>>(x, start_w, start_b, c.pH);

  run_layer<13,1>(c,0,false);
  run_layer<12,2>(c,1,false);
  run_layer<10,1>(c,2,false);
  run_layer< 9,2>(c,3,false);
  run_layer< 7,1>(c,4,false);
  run_layer< 6,2>(c,5,false);
  run_layer< 4,1>(c,6,false);
  run_layer< 3,2>(c,7,true);

  k_head<<<B*N,512,0,stream>>>(c.skipacc, end1_w, end1_b, end2_w, end2_b, (float*)d_out);
}

// Round 6
// 10766.574 us; speedup vs baseline: 4.2484x; 1.2998x over previous
//
#include <hip/hip_runtime.h>
#include <math.h>

#define DIVUP(a,b) (((a)+(b)-1)/(b))

namespace {

constexpr int B=8, T=12, N=883, CIN=3, C=64, E=10, H=8, HD=8, TOPK=48, L=8;
constexpr int SKC=256, F7=7, T13=13;

__device__ __forceinline__ float geluf(float x){ return 0.5f*x*(1.0f+erff(x*0.7071067811865475f)); }
__device__ __forceinline__ float sigmf(float x){ return 1.0f/(1.0f+expf(-x)); }

// ---------------- graph generation ----------------
__global__ void k_dft(const float* __restrict__ x, float* __restrict__ xf){
  int idx = blockIdx.x*256 + threadIdx.x;
  if(idx >= B*F7*N) return;
  int n = idx % N; int f = (idx/N) % F7; int b = idx/(N*F7);
  float re=0.f, im=0.f;
  for(int t=0;t<T;t++){
    float v = x[((size_t)(b*T+t)*N+n)*CIN];
    float ang = -6.283185307179586f * (float)(f*t) / 12.0f;
    re += v*cosf(ang); im += v*sinf(ang);
  }
  xf[idx] = sqrtf(re*re+im*im);
}

__global__ void k_l2f(float* __restrict__ xf){
  int idx = blockIdx.x*256 + threadIdx.x;
  if(idx >= B*N) return;
  int n = idx % N; int b = idx / N;
  float s=0.f;
  for(int f=0;f<F7;f++){ float v=xf[((size_t)b*F7+f)*N+n]; s+=v*v; }
  float inv = 1.0f/fmaxf(sqrtf(s), 1e-12f);
  for(int f=0;f<F7;f++) xf[((size_t)b*F7+f)*N+n] *= inv;
}

__global__ void k_l2n(float* __restrict__ xf){
  int bf = blockIdx.x; int tid = threadIdx.x;
  __shared__ float red[256];
  size_t base = (size_t)bf*N;
  float s=0.f;
  for(int i=tid;i<N;i+=256){ float v=xf[base+i]; s+=v*v; }
  red[tid]=s; __syncthreads();
  for(int k=128;k>0;k>>=1){ if(tid<k) red[tid]+=red[tid+k]; __syncthreads(); }
  float inv = 1.0f/fmaxf(sqrtf(red[0]), 1e-12f);
  __syncthreads();
  for(int i=tid;i<N;i+=256) xf[base+i]*=inv;
}

__global__ void k_x1(const float* __restrict__ x, const float* __restrict__ xf,
                     const float* __restrict__ E3, const float* __restrict__ TiD,
                     const float* __restrict__ DiW, const float* __restrict__ Wx,
                     const float* __restrict__ Wd, float* __restrict__ x1){
  int idx = blockIdx.x*256+threadIdx.x;
  if(idx>=B*N) return;
  int n=idx%N, b=idx/N;
  float xc[40];
  for(int d=0;d<E;d++){
    float a=0.f;
    for(int f=0;f<F7;f++) a += xf[((size_t)b*F7+f)*N+n]*Wx[f*E+d];
    xc[d]=a;
  }
  for(int d=0;d<E;d++) xc[10+d]=E3[n*E+d];
  int ti = (int)(x[((size_t)(b*T+(T-1))*N+n)*CIN+1]*288.0f);
  int dw = (int)(x[((size_t)(b*T+(T-1))*N+n)*CIN+2]);
  for(int d=0;d<E;d++) xc[20+d]=TiD[ti*E+d];
  for(int d=0;d<E;d++) xc[30+d]=DiW[dw*E+d];
  for(int e=0;e<E;e++){
    float a=0.f;
    for(int f=0;f<40;f++) a += xc[f]*Wd[((size_t)n*40+f)*E+e];
    x1[(size_t)idx*E+e]=fmaxf(a,0.f);
  }
}

__global__ void k_lnstats(const float* __restrict__ x1, float* __restrict__ st){
  int b=blockIdx.x, tid=threadIdx.x;
  __shared__ float rs[256], rq[256];
  const int M=N*E;
  float s=0.f,q=0.f;
  for(int i=tid;i<M;i+=256){ float v=x1[(size_t)b*M+i]; s+=v; q+=v*v; }
  rs[tid]=s; rq[tid]=q; __syncthreads();
  for(int k=128;k>0;k>>=1){ if(tid<k){ rs[tid]+=rs[tid+k]; rq[tid]+=rq[tid+k]; } __syncthreads(); }
  if(tid==0){ float mu=rs[0]/M; float var=rq[0]/M-mu*mu; st[b*2]=mu; st[b*2+1]=var; }
}

__global__ void k_dew(const float* __restrict__ x1, const float* __restrict__ st,
                      const float* __restrict__ Wxabs, float* __restrict__ dew){
  int idx=blockIdx.x*256+threadIdx.x;
  if(idx>=B*N) return;
  int b=idx/N;
  float mu=st[b*2], var=st[b*2+1];
  float rs=rsqrtf(var+1e-8f);
  float xk[E];
  for(int e=0;e<E;e++) xk[e]=(x1[(size_t)idx*E+e]-mu)*rs;
  for(int k=0;k<E;k++){
    float a=0.f;
    for(int e=0;e<E;e++) a+=xk[e]*Wxabs[e*E+k];
    dew[(size_t)idx*E+k]=a;
  }
}

__global__ void k_adp(const float* __restrict__ dew, const float* __restrict__ x1,
                      float* __restrict__ adp){
  size_t idx=(size_t)blockIdx.x*256+threadIdx.x;
  if(idx>=(size_t)B*N*N) return;
  int m=(int)(idx%N); int n=(int)((idx/N)%N); int b=(int)(idx/((size_t)N*N));
  const float* dr=dew+((size_t)b*N+n)*E;
  const float* xr=x1+((size_t)b*N+m)*E;
  float a=0.f;
  for(int k=0;k<E;k++) a+=dr[k]*xr[k];
  adp[idx]=fmaxf(a,0.f);
}

__global__ void k_topk(float* __restrict__ adp){
  int row=blockIdx.x, tid=threadIdx.x;
  __shared__ float orig[N];
  __shared__ float work[N];
  __shared__ float rv[256];
  __shared__ int   ri[256];
  for(int i=tid;i<N;i+=256){ float v=adp[(size_t)row*N+i]; orig[i]=v; work[i]=v; }
  __syncthreads();
  for(int k=0;k<TOPK;k++){
    float bv=-1.f; int bi=N;
    for(int i=tid;i<N;i+=256){ float v=work[i]; if(v>bv){bv=v;bi=i;} }
    rv[tid]=bv; ri[tid]=bi; __syncthreads();
    for(int s=128;s>0;s>>=1){
      if(tid<s){
        if(rv[tid+s]>rv[tid] || (rv[tid+s]==rv[tid] && ri[tid+s]<ri[tid])){
          rv[tid]=rv[tid+s]; ri[tid]=ri[tid+s];
        }
      }
      __syncthreads();
    }
    if(tid==0) work[ri[0]] = -2.f;
    __syncthreads();
  }
  float lm=0.f;
  for(int i=tid;i<N;i+=256){ float p=(work[i]<-1.f)?orig[i]:0.f; lm=fmaxf(lm,p); }
  rv[tid]=lm; __syncthreads();
  for(int s=128;s>0;s>>=1){ if(tid<s) rv[tid]=fmaxf(rv[tid],rv[tid+s]); __syncthreads(); }
  float m=rv[0]; __syncthreads();
  float ls=0.f;
  for(int i=tid;i<N;i+=256){ float p=(work[i]<-1.f)?orig[i]:0.f; ls+=expf(p-m); }
  rv[tid]=ls; __syncthreads();
  for(int s=128;s>0;s>>=1){ if(tid<s) rv[tid]+=rv[tid+s]; __syncthreads(); }
  float invZ=1.0f/rv[0]; __syncthreads();
  for(int i=tid;i<N;i+=256){ float p=(work[i]<-1.f)?orig[i]:0.f; adp[(size_t)row*N+i]=expf(p-m)*invZ; }
}

// natural layout: adapN[v][w] = softmax_w(relu(E1@E2^T))[v][w]
__global__ void k_adap(const float* __restrict__ E1, const float* __restrict__ E2,
                       float* __restrict__ adapN){
  int v=blockIdx.x, tid=threadIdx.x;
  __shared__ float rowv[N];
  __shared__ float rv[256];
  float e1[E];
  for(int e=0;e<E;e++) e1[e]=E1[v*E+e];
  for(int j=tid;j<N;j+=256){
    float s=0.f;
    for(int e=0;e<E;e++) s+=e1[e]*E2[j*E+e];
    rowv[j]=fmaxf(s,0.f);
  }
  __syncthreads();
  float lm=-1e30f;
  for(int j=tid;j<N;j+=256) lm=fmaxf(lm,rowv[j]);
  rv[tid]=lm; __syncthreads();
  for(int s=128;s>0;s>>=1){ if(tid<s) rv[tid]=fmaxf(rv[tid],rv[tid+s]); __syncthreads(); }
  float m=rv[0]; __syncthreads();
  float ls=0.f;
  for(int j=tid;j<N;j+=256) ls+=expf(rowv[j]-m);
  rv[tid]=ls; __syncthreads();
  for(int s=128;s>0;s>>=1){ if(tid<s) rv[tid]+=rv[tid+s]; __syncthreads(); }
  float invZ=1.0f/rv[0];
  for(int j=tid;j<N;j+=256) adapN[(size_t)v*N+j]=expf(rowv[j]-m)*invZ;
}

__global__ void k_zero(float* __restrict__ p, int n){
  int idx=blockIdx.x*256+threadIdx.x;
  if(idx<n) p[idx]=0.f;
}

// ---------------- trunk ----------------
__global__ void k_start(const float* __restrict__ x, const float* __restrict__ sw,
                        const float* __restrict__ sb, float* __restrict__ h){
  int idx=blockIdx.x*256+threadIdx.x;
  if(idx>=B*C*N*T13) return;
  int t=idx%T13; int n=(idx/T13)%N; int o=(idx/(T13*N))%C; int b=idx/(T13*N*C);
  float a=sb[o];
  if(t>0){
    size_t xb=((size_t)(b*T+(t-1))*N+n)*CIN;
    for(int i=0;i<CIN;i++) a += sw[i*C+o]*x[xb+i];
  }
  h[idx]=a;
}

// Fused per-(b,n): QKV+gelu+causal attn+FFN+residual+gated dilated conv+skip.
template<int TC, int D>
__global__ __launch_bounds__(256) void k_attconv(const float* __restrict__ hin,
  const float* __restrict__ Wq, const float* __restrict__ bq,
  const float* __restrict__ Wk, const float* __restrict__ bk,
  const float* __restrict__ Wv, const float* __restrict__ bv,
  const float* __restrict__ W1, const float* __restrict__ b1,
  const float* __restrict__ W2, const float* __restrict__ b2,
  const float* __restrict__ fw, const float* __restrict__ fb,
  const float* __restrict__ gw, const float* __restrict__ gb,
  const float* __restrict__ skw, const float* __restrict__ skb,
  float* __restrict__ hT, float* __restrict__ skipacc){
  constexpr int TN = TC - D;
  int bn=blockIdx.x; int tid=threadIdx.x;
  int n=bn%N, b=bn/N;
  __shared__ float sxa [T13*C];
  __shared__ float sq  [T13*C];
  __shared__ float sk  [T13*C];
  __shared__ float sv  [T13*C];
  __shared__ float so  [T13*C];
  __shared__ float shid[T13*4*C];

  for(int idx=tid; idx<TC*C; idx+=256){
    int c=idx/TC, t=idx%TC;
    sxa[t*C+c]=hin[(((size_t)b*C+c)*N+n)*TC+t];
  }
  __syncthreads();

  if(tid<192){
    int m=tid>>6, o=tid&63;
    const float* Wm=(m==0)?Wq:((m==1)?Wk:Wv);
    const float* bm=(m==0)?bq:((m==1)?bk:bv);
    float acc[TC];
    #pragma unroll
    for(int t=0;t<TC;t++) acc[t]=bm[o];
    for(int i=0;i<C;i++){
      float w=Wm[i*C+o];
      #pragma unroll
      for(int t=0;t<TC;t++) acc[t]+=w*sxa[t*C+i];
    }
    float* dst=(m==0)?sq:((m==1)?sk:sv);
    #pragma unroll
    for(int t=0;t<TC;t++) dst[t*C+o]=geluf(acc[t]);
  }
  __syncthreads();

  if(tid<H*TC){
    int hh=tid/TC, t=tid%TC;
    const float* qr=&sq[t*C+hh*HD];
    float att[TC];
    float m=-1e30f;
    #pragma unroll
    for(int s=0;s<TC;s++){
      float a=0.f;
      #pragma unroll
      for(int d=0;d<HD;d++) a+=qr[d]*sk[s*C+hh*HD+d];
      a*=0.3535533905932738f;
      a=(s<=t)?a:-1e30f;
      att[s]=a; m=fmaxf(m,a);
    }
    float Z=0.f;
    #pragma unroll
    for(int s=0;s<TC;s++){ float e=expf(att[s]-m); att[s]=e; Z+=e; }
    float invZ=1.0f/Z;
    #pragma unroll
    for(int d=0;d<HD;d++){
      float o=0.f;
      #pragma unroll
      for(int s=0;s<TC;s++) o+=att[s]*sv[s*C+hh*HD+d];
      so[t*C+hh*HD+d]=o*invZ;
    }
  }
  __syncthreads();

  {
    int j=tid;
    float acc[TC];
    #pragma unroll
    for(int t=0;t<TC;t++) acc[t]=b1[j];
    for(int i=0;i<C;i++){
      float w=W1[(size_t)i*4*C+j];
      #pragma unroll
      for(int t=0;t<TC;t++) acc[t]+=w*so[t*C+i];
    }
    #pragma unroll
    for(int t=0;t<TC;t++) shid[t*4*C+j]=geluf(acc[t]);
  }
  __syncthreads();

  {
    int o=tid&63, part=tid>>6;
    float acc[TC];
    #pragma unroll
    for(int t=0;t<TC;t++) acc[t]=(part==0)?b2[o]:0.f;
    for(int jj=0;jj<64;jj++){
      int j=part*64+jj;
      float w=W2[(size_t)j*C+o];
      #pragma unroll
      for(int t=0;t<TC;t++) acc[t]+=w*shid[t*4*C+j];
    }
    if(part==1){
      #pragma unroll
      for(int t=0;t<TC;t++) sq[t*C+o]=acc[t];
    }else if(part==2){
      #pragma unroll
      for(int t=0;t<TC;t++) sk[t*C+o]=acc[t];
    }else if(part==3){
      #pragma unroll
      for(int t=0;t<TC;t++) sv[t*C+o]=acc[t];
    }
    __syncthreads();
    if(part==0){
      #pragma unroll
      for(int t=0;t<TC;t++){
        float fin=acc[t]+sq[t*C+o]+sk[t*C+o]+sv[t*C+o]+sxa[t*C+o];
        shid[t*C+o]=fin;
      }
    }
  }
  __syncthreads();

  if(tid<128){
    int c=tid&63, m=tid>>6;
    const float* base=m?gw:fw;
    float acc[TN];
    #pragma unroll
    for(int tt=0;tt<TN;tt++) acc[tt]=0.f;
    for(int i=0;i<C;i++){
      float w0=base[i*C+c];
      float w1=base[C*C+i*C+c];
      #pragma unroll
      for(int tt=0;tt<TN;tt++) acc[tt]+=w0*shid[tt*C+i]+w1*shid[(tt+D)*C+i];
    }
    float bi=m?gb[c]:fb[c];
    if(m==0){
      #pragma unroll
      for(int tt=0;tt<TN;tt++) sq[tt*C+c]=tanhf(acc[tt]+bi);
    }else{
      #pragma unroll
      for(int tt=0;tt<TN;tt++) sk[tt*C+c]=sigmf(acc[tt]+bi);
    }
  }
  __syncthreads();

  if(tid<C) so[tid]=sq[(TN-1)*C+tid]*sk[(TN-1)*C+tid];
  __syncthreads();

  {
    float a=skb[tid];
    for(int i=0;i<C;i++) a+=so[i]*skw[i*SKC+tid];
    skipacc[((size_t)b*SKC+tid)*N+n]+=a;
  }

  size_t obase=(size_t)bn*C*TN;
  for(int idx=tid; idx<C*TN; idx+=256){
    int c=idx/TN, tt=idx%TN;
    hT[obase+idx]=sq[tt*C+c]*sk[tt*C+c];
  }
}

// Pair-batched spatial GEMM.
// Semantics: Y_j[w][col] = sum_v M_j[w][v] * X[v][col], where
//   aT==0: A given in natural [v][w] layout (2D supports: M[w][v]=A[v][w])
//   aT==1: A given in row-major [w][v] layout (AD: M[w][v]=A[w][v])
// X,Y are (…,N,M) slabs; j selects support within the pair; M % 64 == 0.
__global__ __launch_bounds__(256) void k_spatial2(
    const float* __restrict__ A0, const float* __restrict__ A1,
    long long st0, long long st1, int aT0, int aT1,
    const float* __restrict__ X, int xPerJ,
    float* __restrict__ Y, int M, int nMB){
  __shared__ float As[64][68];   // [k_local][r_local]
  __shared__ float Bs[64][68];   // [k_local][col_local]
  int b=blockIdx.z;
  int j=blockIdx.y/nMB, mb=blockIdx.y%nMB;
  const float* Ab; int aT;
  if(j==0){ Ab=A0+(size_t)b*st0; aT=aT0; } else { Ab=A1+(size_t)b*st1; aT=aT1; }
  const float* Xb = X + (size_t)(xPerJ ? (j*B+b) : b)*N*M;
  float* Yb = Y + (size_t)(j*B+b)*N*M;
  int tid=threadIdx.x;
  int lrow=tid>>6, lcol=tid&63;
  int tx=tid&15, ty=tid>>4;
  int rowBase=blockIdx.x*64, colBase=mb*64;
  float acc[4][4];
  #pragma unroll
  for(int i=0;i<4;i++){
    #pragma unroll
    for(int jj=0;jj<4;jj++) acc[i][jj]=0.f;
  }
  for(int k0=0;k0<N;k0+=64){
    if(aT==0){
      #pragma unroll
      for(int e=0;e<16;e++){
        int row=lrow+e*4;
        int ak=k0+row, ar=rowBase+lcol;
        As[row][lcol]=(ak<N&&ar<N)?Ab[(size_t)ak*N+ar]:0.f;  // coalesced, conflict-free
        int bk=k0+row;
        Bs[row][lcol]=(bk<N)?Xb[(size_t)bk*M+colBase+lcol]:0.f;
      }
    }else{
      #pragma unroll
      for(int e=0;e<16;e++){
        int row=lrow+e*4;
        int ar=rowBase+row, ak=k0+lcol;
        As[lcol][row]=(ar<N&&ak<N)?Ab[(size_t)ar*N+ak]:0.f;  // transposed store
        int bk=k0+row;
        Bs[row][lcol]=(bk<N)?Xb[(size_t)bk*M+colBase+lcol]:0.f;
      }
    }
    __syncthreads();
    #pragma unroll 4
    for(int kk=0;kk<64;kk++){
      float4 bv=*(const float4*)&Bs[kk][tx*4];
      float4 av=*(const float4*)&As[kk][ty*4];
      acc[0][0]+=av.x*bv.x; acc[0][1]+=av.x*bv.y; acc[0][2]+=av.x*bv.z; acc[0][3]+=av.x*bv.w;
      acc[1][0]+=av.y*bv.x; acc[1][1]+=av.y*bv.y; acc[1][2]+=av.y*bv.z; acc[1][3]+=av.y*bv.w;
      acc[2][0]+=av.z*bv.x; acc[2][1]+=av.z*bv.y; acc[2][2]+=av.z*bv.z; acc[2][3]+=av.z*bv.w;
      acc[3][0]+=av.w*bv.x; acc[3][1]+=av.w*bv.y; acc[3][2]+=av.w*bv.z; acc[3][3]+=av.w*bv.w;
    }
    __syncthreads();
  }
  #pragma unroll
  for(int i=0;i<4;i++){
    int r=rowBase+ty*4+i;
    if(r<N){
      float4 v; v.x=acc[i][0]; v.y=acc[i][1]; v.z=acc[i][2]; v.w=acc[i][3];
      *(float4*)&Yb[(size_t)r*M+colBase+tx*4]=v;
    }
  }
}

// fused GCN projection over NS = FIRST + 2*NPAIR slices.
// Slice order: [hT(if FIRST)], P0, Q0 [, P1, Q1]; W chunks Wg + j*C*C in same order.
template<int TN, int NPAIR, int FIRST>
__global__ __launch_bounds__(256) void k_gcnproj(const float* __restrict__ hT,
    const float* __restrict__ P, const float* __restrict__ Q,
    const float* __restrict__ Wg, const float* __restrict__ gb,
    const float* __restrict__ res, float* __restrict__ acc, int Tc){
  constexpr int NS = FIRST + 2*NPAIR;
  constexpr int SL = C*TN;
  constexpr int LDSF = ((NS*C > 256) ? NS*C : 256)*TN;
  int bn=blockIdx.x; int tid=threadIdx.x;
  int n=bn%N, b=bn/N;
  __shared__ float sx[LDSF];
  int base=0;
  if(FIRST){
    const float* s0=hT+(size_t)bn*SL;
    for(int i=tid;i<SL;i+=256) sx[i]=s0[i];
    base=1;
  }
  for(int jj=0;jj<NPAIR;jj++){
    const float* ps=P+((size_t)jj*B*N+bn)*SL;
    const float* qs=Q+((size_t)jj*B*N+bn)*SL;
    for(int i=tid;i<SL;i+=256){
      sx[(base+2*jj)*SL+i]=ps[i];
      sx[(base+2*jj+1)*SL+i]=qs[i];
    }
  }
  __syncthreads();
  int o=tid&63, part=tid>>6;
  float a[TN];
  #pragma unroll
  for(int tt=0;tt<TN;tt++) a[tt]=0.f;
  for(int j=0;j<NS;j++){
    const float* Wj=Wg+(size_t)j*C*C;
    const float* xj=&sx[j*SL];
    for(int ii=0;ii<16;ii++){
      int i=part*16+ii;
      float w=Wj[i*C+o];
      #pragma unroll
      for(int tt=0;tt<TN;tt++) a[tt]+=w*xj[i*TN+tt];
    }
  }
  __syncthreads();
  float* red=sx;
  #pragma unroll
  for(int tt=0;tt<TN;tt++) red[(part*64+o)*TN+tt]=a[tt];
  __syncthreads();
  if(part==0){
    size_t ob=(((size_t)b*C+o)*N+n)*TN;
    float v[TN];
    #pragma unroll
    for(int tt=0;tt<TN;tt++)
      v[tt]=red[o*TN+tt]+red[(64+o)*TN+tt]+red[(128+o)*TN+tt]+red[(192+o)*TN+tt];
    if(FIRST){
      float g=gb[o];
      size_t rb=(((size_t)b*C+o)*N+n)*Tc+(Tc-TN);
      #pragma unroll
      for(int tt=0;tt<TN;tt++) acc[ob+tt]=v[tt]+g+res[rb+tt];
    }else{
      #pragma unroll
      for(int tt=0;tt<TN;tt++) acc[ob+tt]+=v[tt];
    }
  }
}

__global__ void k_bnstats(const float* __restrict__ h, float* __restrict__ st, int tn){
  int c=blockIdx.x, tid=threadIdx.x;
  __shared__ float rs[256], rq[256];
  const int Mi=N*tn;
  const int M=B*Mi;
  float s=0.f,q=0.f;
  for(int idx=tid; idx<M; idx+=256){
    int b=idx/Mi; int inner=idx%Mi;
    float v=h[(size_t)b*C*Mi + (size_t)c*Mi + inner];
    s+=v; q+=v*v;
  }
  rs[tid]=s; rq[tid]=q; __syncthreads();
  for(int k=128;k>0;k>>=1){ if(tid<k){ rs[tid]+=rs[tid+k]; rq[tid]+=rq[tid+k]; } __syncthreads(); }
  if(tid==0){
    float mu=rs[0]/M; float var=rq[0]/M-mu*mu;
    st[c]=mu; st[C+c]=rsqrtf(var+1e-5f);
  }
}

__global__ void k_bnapply(float* __restrict__ h, const float* __restrict__ st,
                          const float* __restrict__ g, const float* __restrict__ bb, int tn){
  int idx=blockIdx.x*256+threadIdx.x;
  if(idx>=B*C*N*tn) return;
  int c=(idx/(N*tn))%C;
  float v=h[idx];
  h[idx]=(v-st[c])*st[C+c]*g[c]+bb[c];
}

__global__ void k_head(const float* __restrict__ skipacc, const float* __restrict__ W1,
  const float* __restrict__ b1, const float* __restrict__ W2, const float* __restrict__ b2,
  float* __restrict__ out){
  int gid=blockIdx.x; int tid=threadIdx.x;  // 512 threads
  int n=gid%N; int b=gid/N;
  __shared__ float s[SKC];
  __shared__ float hid[512];
  if(tid<SKC){
    float v=skipacc[((size_t)b*SKC+tid)*N+n];
    s[tid]=fmaxf(v,0.f);
  }
  __syncthreads();
  {
    float a=b1[tid];
    for(int i=0;i<SKC;i++) a+=s[i]*W1[(size_t)i*512+tid];
    hid[tid]=fmaxf(a,0.f);
  }
  __syncthreads();
  if(tid<T){
    float a=b2[tid];
    for(int j=0;j<512;j++) a+=hid[j]*W2[(size_t)j*T+tid];
    out[((size_t)b*T+tid)*N+n]=a;
  }
}

// ---------------- host-side layer driver ----------------
struct Ctx {
  const float *Wq,*bq,*Wk,*bk,*Wv,*bv,*W1,*b1,*W2,*b2;
  const float *filt_w,*filt_b,*gate_w,*gate_b,*skip_w,*skip_b,*gcn_w,*gcn_b,*bn_g,*bn_b;
  const float *sup0,*sup1;
  float *adapN,*adpAD;
  float *pH,*pAlt,*hT,*Pb,*Qb,*skipacc,*bnst;
  bool grouped;
  hipStream_t stream;
};

template<int TC, int D>
void run_layer(Ctx& c, int l, bool last){
  constexpr int TN=TC-D;
  const size_t CC=(size_t)C*C;
  k_attconv<TC,D><<<B*N,256,0,c.stream>>>(c.pH,
    c.Wq+(size_t)l*CC, c.bq+(size_t)l*C,
    c.Wk+(size_t)l*CC, c.bk+(size_t)l*C,
    c.Wv+(size_t)l*CC, c.bv+(size_t)l*C,
    c.W1+(size_t)l*C*4*C, c.b1+(size_t)l*4*C,
    c.W2+(size_t)l*4*C*C, c.b2+(size_t)l*C,
    c.filt_w+(size_t)l*2*CC, c.filt_b+(size_t)l*C,
    c.gate_w+(size_t)l*2*CC, c.gate_b+(size_t)l*C,
    c.skip_w+(size_t)l*C*SKC, c.skip_b+(size_t)l*SKC,
    c.hT, c.skipacc);
  if(!last){
    int M=C*TN, nMB=M/64;
    const long long NN=(long long)N*N;
    const float* Wl=c.gcn_w+(size_t)l*9*CC;
    if(c.grouped){
      dim3 sg(DIVUP(N,64), 2*nMB, B);
      // group 0: support0, support1 (natural [v][w])
      k_spatial2<<<sg,256,0,c.stream>>>(c.sup0,c.sup1, 0,0, 0,0, c.hT,0, c.Pb, M,nMB);
      k_spatial2<<<sg,256,0,c.stream>>>(c.sup0,c.sup1, 0,0, 0,0, c.Pb,1, c.Qb, M,nMB);
      k_gcnproj<TN,2,1><<<B*N,256,0,c.stream>>>(c.hT,c.Pb,c.Qb,
          Wl, c.gcn_b+(size_t)l*C, c.pH, c.pAlt, TC);
      // group 1: Adap (natural), AD (row-major per-b)
      k_spatial2<<<sg,256,0,c.stream>>>(c.adapN,c.adpAD, 0,NN, 0,1, c.hT,0, c.Pb, M,nMB);
      k_spatial2<<<sg,256,0,c.stream>>>(c.adapN,c.adpAD, 0,NN, 0,1, c.Pb,1, c.Qb, M,nMB);
      k_gcnproj<TN,2,0><<<B*N,256,0,c.stream>>>(c.hT,c.Pb,c.Qb,
          Wl+5*CC, nullptr, nullptr, c.pAlt, TC);
    }else{
      dim3 sg(DIVUP(N,64), nMB, B);
      const float* Aps[4]={c.sup0,c.sup1,c.adapN,c.adpAD};
      const long long Ast[4]={0,0,0,NN};
      const int aTs[4]={0,0,0,1};
      for(int s=0;s<4;s++){
        k_spatial2<<<sg,256,0,c.stream>>>(Aps[s],Aps[s],Ast[s],Ast[s],aTs[s],aTs[s],
            c.hT,0, c.Pb, M,nMB);
        k_spatial2<<<sg,256,0,c.stream>>>(Aps[s],Aps[s],Ast[s],Ast[s],aTs[s],aTs[s],
            c.Pb,1, c.Qb, M,nMB);
        if(s==0){
          k_gcnproj<TN,1,1><<<B*N,256,0,c.stream>>>(c.hT,c.Pb,c.Qb,
              Wl, c.gcn_b+(size_t)l*C, c.pH, c.pAlt, TC);
        }else{
          k_gcnproj<TN,1,0><<<B*N,256,0,c.stream>>>(c.hT,c.Pb,c.Qb,
              Wl+(size_t)(1+2*s)*CC, nullptr, nullptr, c.pAlt, TC);
        }
      }
    }
    k_bnstats<<<C,256,0,c.stream>>>(c.pAlt, c.bnst, TN);
    k_bnapply<<<DIVUP(B*C*N*TN,256),256,0,c.stream>>>(c.pAlt, c.bnst,
      c.bn_g+(size_t)l*C, c.bn_b+(size_t)l*C, TN);
    float* tmp=c.pH; c.pH=c.pAlt; c.pAlt=tmp;
  }
}

} // namespace

extern "C" void kernel_launch(void* const* d_in, const int* in_sizes, int n_in,
                              void* d_out, int out_size, void* d_ws, size_t ws_size,
                              hipStream_t stream){
  (void)in_sizes; (void)n_in;
  const float* x      =(const float*)d_in[0];
  const float* TiD    =(const float*)d_in[3];
  const float* DiW    =(const float*)d_in[4];
  const float* E1     =(const float*)d_in[5];
  const float* E2     =(const float*)d_in[6];
  const float* E3     =(const float*)d_in[7];
  const float* Wx     =(const float*)d_in[8];
  const float* Wd     =(const float*)d_in[9];
  const float* Wxabs  =(const float*)d_in[10];
  const float* start_w=(const float*)d_in[11];
  const float* start_b=(const float*)d_in[12];

  Ctx c;
  c.sup0=(const float*)d_in[1]; c.sup1=(const float*)d_in[2];
  c.Wq=(const float*)d_in[13]; c.bq=(const float*)d_in[14];
  c.Wk=(const float*)d_in[15]; c.bk=(const float*)d_in[16];
  c.Wv=(const float*)d_in[17]; c.bv=(const float*)d_in[18];
  c.W1=(const float*)d_in[19]; c.b1=(const float*)d_in[20];
  c.W2=(const float*)d_in[21]; c.b2=(const float*)d_in[22];
  c.filt_w=(const float*)d_in[23]; c.filt_b=(const float*)d_in[24];
  c.gate_w=(const float*)d_in[25]; c.gate_b=(const float*)d_in[26];
  c.skip_w=(const float*)d_in[27]; c.skip_b=(const float*)d_in[28];
  c.gcn_w =(const float*)d_in[29]; c.gcn_b =(const float*)d_in[30];
  c.bn_g  =(const float*)d_in[31]; c.bn_b  =(const float*)d_in[32];
  const float* end1_w =(const float*)d_in[33];
  const float* end1_b =(const float*)d_in[34];
  const float* end2_w =(const float*)d_in[35];
  const float* end2_b =(const float*)d_in[36];
  c.stream=stream;

  size_t off=0;
  auto alloc=[&](size_t nf)->float*{
    nf=(nf+3)&~(size_t)3;
    float* p=(float*)((char*)d_ws+off);
    off += nf*sizeof(float);
    return p;
  };
  const size_t HMAX =(size_t)B*C*N*T13;
  const size_t HT12 =(size_t)B*C*N*12;
  float* xf     = alloc((size_t)B*F7*N);
  float* gx1    = alloc((size_t)B*N*E);
  float* gdew   = alloc((size_t)B*N*E);
  float* gst    = alloc(16);
  c.bnst        = alloc(2*C);
  c.adpAD       = alloc((size_t)B*N*N);
  c.adapN       = alloc((size_t)N*N);
  c.pH          = alloc(HMAX);
  c.pAlt        = alloc(HMAX);
  c.hT          = alloc(HT12);
  c.skipacc     = alloc((size_t)B*SKC*N);
  size_t base_bytes = off;
  const size_t HT12p = (HT12+3)&~(size_t)3;
  size_t grouped_bytes = base_bytes + 4*HT12p*sizeof(float);
  size_t single_bytes  = base_bytes + 2*HT12p*sizeof(float);
  if(ws_size >= grouped_bytes){
    c.grouped=true;
    c.Pb = alloc(2*HT12);
    c.Qb = alloc(2*HT12);
  }else if(ws_size >= single_bytes){
    c.grouped=false;
    c.Pb = alloc(HT12);
    c.Qb = alloc(HT12);
  }else{
    k_zero<<<DIVUP(out_size,256),256,0,stream>>>((float*)d_out, out_size);
    return;
  }

  // ---- graph generation ----
  k_dft <<<DIVUP(B*F7*N,256),256,0,stream>>>(x, xf);
  k_l2f <<<DIVUP(B*N,256),256,0,stream>>>(xf);
  k_l2n <<<B*F7,256,0,stream>>>(xf);
  k_x1  <<<DIVUP(B*N,256),256,0,stream>>>(x, xf, E3, TiD, DiW, Wx, Wd, gx1);
  k_lnstats<<<B,256,0,stream>>>(gx1, gst);
  k_dew <<<DIVUP(B*N,256),256,0,stream>>>(gx1, gst, Wxabs, gdew);
  k_adp <<<DIVUP(B*N*N,256),256,0,stream>>>(gdew, gx1, c.adpAD);
  k_topk<<<B*N,256,0,stream>>>(c.adpAD);
  k_adap<<<N,256,0,stream>>>(E1, E2, c.adapN);

  // ---- trunk ----
  k_zero<<<DIVUP(B*SKC*N,256),256,0,stream>>>(c.skipacc, B*SKC*N);
  k_start<<<DIVUP(B*C*N*T13,256),256,0,stream>>>(x, start_w, start_b, c.pH);

  run_layer<13,1>(c,0,false);
  run_layer<12,2>(c,1,false);
  run_layer<10,1>(c,2,false);
  run_layer< 9,2>(c,3,false);
  run_layer< 7,1>(c,4,false);
  run_layer< 6,2>(c,5,false);
  run_layer< 4,1>(c,6,false);
  run_layer< 3,2>(c,7,true);

  k_head<<<B*N,512,0,stream>>>(c.skipacc, end1_w, end1_b, end2_w, end2_b, (float*)d_out);
}

// Round 7
// 6352.026 us; speedup vs baseline: 7.2010x; 1.6950x over previous
//
#include <hip/hip_runtime.h>
#include <math.h>

#define DIVUP(a,b) (((a)+(b)-1)/(b))

namespace {

constexpr int B=8, T=12, N=883, CIN=3, C=64, E=10, H=8, HD=8, TOPK=48, L=8;
constexpr int SKC=256, F7=7, T13=13;
constexpr int NP=896;   // padded N for bf16 support matrices (mult of 64, 16B-aligned rows)

__device__ __forceinline__ float geluf(float x){ return 0.5f*x*(1.0f+erff(x*0.7071067811865475f)); }
__device__ __forceinline__ float sigmf(float x){ return 1.0f/(1.0f+expf(-x)); }
__device__ __forceinline__ float us2f(unsigned short u){ return __uint_as_float(((unsigned)u)<<16); }
__device__ __forceinline__ unsigned short f2us(float f){
  unsigned x=__float_as_uint(f);
  return (unsigned short)((x + 0x7fffu + ((x>>16)&1u))>>16);
}

// ---------------- graph generation ----------------
__global__ void k_dft(const float* __restrict__ x, float* __restrict__ xf){
  int idx = blockIdx.x*256 + threadIdx.x;
  if(idx >= B*F7*N) return;
  int n = idx % N; int f = (idx/N) % F7; int b = idx/(N*F7);
  float re=0.f, im=0.f;
  for(int t=0;t<T;t++){
    float v = x[((size_t)(b*T+t)*N+n)*CIN];
    float ang = -6.283185307179586f * (float)(f*t) / 12.0f;
    re += v*cosf(ang); im += v*sinf(ang);
  }
  xf[idx] = sqrtf(re*re+im*im);
}

__global__ void k_l2f(float* __restrict__ xf){
  int idx = blockIdx.x*256 + threadIdx.x;
  if(idx >= B*N) return;
  int n = idx % N; int b = idx / N;
  float s=0.f;
  for(int f=0;f<F7;f++){ float v=xf[((size_t)b*F7+f)*N+n]; s+=v*v; }
  float inv = 1.0f/fmaxf(sqrtf(s), 1e-12f);
  for(int f=0;f<F7;f++) xf[((size_t)b*F7+f)*N+n] *= inv;
}

__global__ void k_l2n(float* __restrict__ xf){
  int bf = blockIdx.x; int tid = threadIdx.x;
  __shared__ float red[256];
  size_t base = (size_t)bf*N;
  float s=0.f;
  for(int i=tid;i<N;i+=256){ float v=xf[base+i]; s+=v*v; }
  red[tid]=s; __syncthreads();
  for(int k=128;k>0;k>>=1){ if(tid<k) red[tid]+=red[tid+k]; __syncthreads(); }
  float inv = 1.0f/fmaxf(sqrtf(red[0]), 1e-12f);
  __syncthreads();
  for(int i=tid;i<N;i+=256) xf[base+i]*=inv;
}

__global__ void k_x1(const float* __restrict__ x, const float* __restrict__ xf,
                     const float* __restrict__ E3, const float* __restrict__ TiD,
                     const float* __restrict__ DiW, const float* __restrict__ Wx,
                     const float* __restrict__ Wd, float* __restrict__ x1){
  int idx = blockIdx.x*256+threadIdx.x;
  if(idx>=B*N) return;
  int n=idx%N, b=idx/N;
  float xc[40];
  for(int d=0;d<E;d++){
    float a=0.f;
    for(int f=0;f<F7;f++) a += xf[((size_t)b*F7+f)*N+n]*Wx[f*E+d];
    xc[d]=a;
  }
  for(int d=0;d<E;d++) xc[10+d]=E3[n*E+d];
  int ti = (int)(x[((size_t)(b*T+(T-1))*N+n)*CIN+1]*288.0f);
  int dw = (int)(x[((size_t)(b*T+(T-1))*N+n)*CIN+2]);
  for(int d=0;d<E;d++) xc[20+d]=TiD[ti*E+d];
  for(int d=0;d<E;d++) xc[30+d]=DiW[dw*E+d];
  for(int e=0;e<E;e++){
    float a=0.f;
    for(int f=0;f<40;f++) a += xc[f]*Wd[((size_t)n*40+f)*E+e];
    x1[(size_t)idx*E+e]=fmaxf(a,0.f);
  }
}

__global__ void k_lnstats(const float* __restrict__ x1, float* __restrict__ st){
  int b=blockIdx.x, tid=threadIdx.x;
  __shared__ float rs[256], rq[256];
  const int M=N*E;
  float s=0.f,q=0.f;
  for(int i=tid;i<M;i+=256){ float v=x1[(size_t)b*M+i]; s+=v; q+=v*v; }
  rs[tid]=s; rq[tid]=q; __syncthreads();
  for(int k=128;k>0;k>>=1){ if(tid<k){ rs[tid]+=rs[tid+k]; rq[tid]+=rq[tid+k]; } __syncthreads(); }
  if(tid==0){ float mu=rs[0]/M; float var=rq[0]/M-mu*mu; st[b*2]=mu; st[b*2+1]=var; }
}

__global__ void k_dew(const float* __restrict__ x1, const float* __restrict__ st,
                      const float* __restrict__ Wxabs, float* __restrict__ dew){
  int idx=blockIdx.x*256+threadIdx.x;
  if(idx>=B*N) return;
  int b=idx/N;
  float mu=st[b*2], var=st[b*2+1];
  float rs=rsqrtf(var+1e-8f);
  float xk[E];
  for(int e=0;e<E;e++) xk[e]=(x1[(size_t)idx*E+e]-mu)*rs;
  for(int k=0;k<E;k++){
    float a=0.f;
    for(int e=0;e<E;e++) a+=xk[e]*Wxabs[e*E+k];
    dew[(size_t)idx*E+k]=a;
  }
}

__global__ void k_adp(const float* __restrict__ dew, const float* __restrict__ x1,
                      float* __restrict__ adp){
  size_t idx=(size_t)blockIdx.x*256+threadIdx.x;
  if(idx>=(size_t)B*N*N) return;
  int m=(int)(idx%N); int n=(int)((idx/N)%N); int b=(int)(idx/((size_t)N*N));
  const float* dr=dew+((size_t)b*N+n)*E;
  const float* xr=x1+((size_t)b*N+m)*E;
  float a=0.f;
  for(int k=0;k<E;k++) a+=dr[k]*xr[k];
  adp[idx]=fmaxf(a,0.f);
}

// adp row -> softmax(adp*mask(top48)) row, written as bf16 hi/lo into padded AD mats
__global__ void k_topk(float* __restrict__ adp,
                       unsigned short* __restrict__ ADhi, unsigned short* __restrict__ ADlo){
  int row=blockIdx.x, tid=threadIdx.x;
  __shared__ float orig[N];
  __shared__ float work[N];
  __shared__ float rv[256];
  __shared__ int   ri[256];
  for(int i=tid;i<N;i+=256){ float v=adp[(size_t)row*N+i]; orig[i]=v; work[i]=v; }
  __syncthreads();
  for(int k=0;k<TOPK;k++){
    float bv=-1.f; int bi=N;
    for(int i=tid;i<N;i+=256){ float v=work[i]; if(v>bv){bv=v;bi=i;} }
    rv[tid]=bv; ri[tid]=bi; __syncthreads();
    for(int s=128;s>0;s>>=1){
      if(tid<s){
        if(rv[tid+s]>rv[tid] || (rv[tid+s]==rv[tid] && ri[tid+s]<ri[tid])){
          rv[tid]=rv[tid+s]; ri[tid]=ri[tid+s];
        }
      }
      __syncthreads();
    }
    if(tid==0) work[ri[0]] = -2.f;
    __syncthreads();
  }
  float lm=0.f;
  for(int i=tid;i<N;i+=256){ float p=(work[i]<-1.f)?orig[i]:0.f; lm=fmaxf(lm,p); }
  rv[tid]=lm; __syncthreads();
  for(int s=128;s>0;s>>=1){ if(tid<s) rv[tid]=fmaxf(rv[tid],rv[tid+s]); __syncthreads(); }
  float m=rv[0]; __syncthreads();
  float ls=0.f;
  for(int i=tid;i<N;i+=256){ float p=(work[i]<-1.f)?orig[i]:0.f; ls+=expf(p-m); }
  rv[tid]=ls; __syncthreads();
  for(int s=128;s>0;s>>=1){ if(tid<s) rv[tid]+=rv[tid+s]; __syncthreads(); }
  float invZ=1.0f/rv[0]; __syncthreads();
  size_t base=((size_t)(row/N)*NP + (size_t)(row%N))*NP;
  for(int i=tid;i<N;i+=256){
    float p=(work[i]<-1.f)?orig[i]:0.f;
    float f=expf(p-m)*invZ;
    unsigned short h=f2us(f);
    ADhi[base+i]=h; ADlo[base+i]=f2us(f-us2f(h));
  }
}

// adapT[w][v] = softmax_row(relu(E1@E2^T))[v][w], bf16 hi/lo, padded stride NP
__global__ void k_adap(const float* __restrict__ E1, const float* __restrict__ E2,
                       unsigned short* __restrict__ Mh, unsigned short* __restrict__ Ml){
  int v=blockIdx.x, tid=threadIdx.x;
  __shared__ float rowv[N];
  __shared__ float rv[256];
  float e1[E];
  for(int e=0;e<E;e++) e1[e]=E1[v*E+e];
  for(int j=tid;j<N;j+=256){
    float s=0.f;
    for(int e=0;e<E;e++) s+=e1[e]*E2[j*E+e];
    rowv[j]=fmaxf(s,0.f);
  }
  __syncthreads();
  float lm=-1e30f;
  for(int j=tid;j<N;j+=256) lm=fmaxf(lm,rowv[j]);
  rv[tid]=lm; __syncthreads();
  for(int s=128;s>0;s>>=1){ if(tid<s) rv[tid]=fmaxf(rv[tid],rv[tid+s]); __syncthreads(); }
  float m=rv[0]; __syncthreads();
  float ls=0.f;
  for(int j=tid;j<N;j+=256) ls+=expf(rowv[j]-m);
  rv[tid]=ls; __syncthreads();
  for(int s=128;s>0;s>>=1){ if(tid<s) rv[tid]+=rv[tid+s]; __syncthreads(); }
  float invZ=1.0f/rv[0];
  for(int j=tid;j<N;j+=256){
    float f=expf(rowv[j]-m)*invZ;
    unsigned short h=f2us(f);
    Mh[(size_t)j*NP+v]=h; Ml[(size_t)j*NP+v]=f2us(f-us2f(h));
  }
}

// transpose+split fp32 support -> bf16 hi/lo M[w][v]=A[v][w], padded stride NP
__global__ void k_cvtT(const float* __restrict__ A, unsigned short* __restrict__ Mh,
                       unsigned short* __restrict__ Ml){
  int idx=blockIdx.x*256+threadIdx.x;
  if(idx>=N*N) return;
  int w=idx/N, v=idx%N;
  float f=A[(size_t)v*N+w];
  unsigned short h=f2us(f);
  Mh[(size_t)w*NP+v]=h;
  Ml[(size_t)w*NP+v]=f2us(f-us2f(h));
}

__global__ void k_zero(float* __restrict__ p, int n){
  int idx=blockIdx.x*256+threadIdx.x;
  if(idx<n) p[idx]=0.f;
}
__global__ void k_zeroUS(unsigned short* __restrict__ p, long long n){
  long long idx=(long long)blockIdx.x*256+threadIdx.x;
  if(idx<n) p[idx]=0;
}

// ---------------- trunk ----------------
__global__ void k_start(const float* __restrict__ x, const float* __restrict__ sw,
                        const float* __restrict__ sb, float* __restrict__ h){
  int idx=blockIdx.x*256+threadIdx.x;
  if(idx>=B*C*N*T13) return;
  int t=idx%T13; int n=(idx/T13)%N; int o=(idx/(T13*N))%C; int b=idx/(T13*N*C);
  float a=sb[o];
  if(t>0){
    size_t xb=((size_t)(b*T+(t-1))*N+n)*CIN;
    for(int i=0;i<CIN;i++) a += sw[i*C+o]*x[xb+i];
  }
  h[idx]=a;
}

// Fused per-(b,n): QKV+gelu+causal attn+FFN+residual+gated dilated conv+skip.
// Writes hT as bf16 hi/lo ([b][n][c][tt]) and skipacc += (last column skip proj).
template<int TC, int D>
__global__ __launch_bounds__(256) void k_attconv(const float* __restrict__ hin,
  const float* __restrict__ Wq, const float* __restrict__ bq,
  const float* __restrict__ Wk, const float* __restrict__ bk,
  const float* __restrict__ Wv, const float* __restrict__ bv,
  const float* __restrict__ W1, const float* __restrict__ b1,
  const float* __restrict__ W2, const float* __restrict__ b2,
  const float* __restrict__ fw, const float* __restrict__ fb,
  const float* __restrict__ gw, const float* __restrict__ gb,
  const float* __restrict__ skw, const float* __restrict__ skb,
  unsigned short* __restrict__ hThi, unsigned short* __restrict__ hTlo,
  float* __restrict__ skipacc){
  constexpr int TN = TC - D;
  int bn=blockIdx.x; int tid=threadIdx.x;
  int n=bn%N, b=bn/N;
  __shared__ float sxa [T13*C];
  __shared__ float sq  [T13*C];
  __shared__ float sk  [T13*C];
  __shared__ float sv  [T13*C];
  __shared__ float so  [T13*C];
  __shared__ float shid[T13*4*C];

  for(int idx=tid; idx<TC*C; idx+=256){
    int c=idx/TC, t=idx%TC;
    sxa[t*C+c]=hin[(((size_t)b*C+c)*N+n)*TC+t];
  }
  __syncthreads();

  if(tid<192){
    int m=tid>>6, o=tid&63;
    const float* Wm=(m==0)?Wq:((m==1)?Wk:Wv);
    const float* bm=(m==0)?bq:((m==1)?bk:bv);
    float acc[TC];
    #pragma unroll
    for(int t=0;t<TC;t++) acc[t]=bm[o];
    for(int i=0;i<C;i++){
      float w=Wm[i*C+o];
      #pragma unroll
      for(int t=0;t<TC;t++) acc[t]+=w*sxa[t*C+i];
    }
    float* dst=(m==0)?sq:((m==1)?sk:sv);
    #pragma unroll
    for(int t=0;t<TC;t++) dst[t*C+o]=geluf(acc[t]);
  }
  __syncthreads();

  if(tid<H*TC){
    int hh=tid/TC, t=tid%TC;
    const float* qr=&sq[t*C+hh*HD];
    float att[TC];
    float m=-1e30f;
    #pragma unroll
    for(int s=0;s<TC;s++){
      float a=0.f;
      #pragma unroll
      for(int d=0;d<HD;d++) a+=qr[d]*sk[s*C+hh*HD+d];
      a*=0.3535533905932738f;
      a=(s<=t)?a:-1e30f;
      att[s]=a; m=fmaxf(m,a);
    }
    float Z=0.f;
    #pragma unroll
    for(int s=0;s<TC;s++){ float e=expf(att[s]-m); att[s]=e; Z+=e; }
    float invZ=1.0f/Z;
    #pragma unroll
    for(int d=0;d<HD;d++){
      float o=0.f;
      #pragma unroll
      for(int s=0;s<TC;s++) o+=att[s]*sv[s*C+hh*HD+d];
      so[t*C+hh*HD+d]=o*invZ;
    }
  }
  __syncthreads();

  {
    int j=tid;
    float acc[TC];
    #pragma unroll
    for(int t=0;t<TC;t++) acc[t]=b1[j];
    for(int i=0;i<C;i++){
      float w=W1[(size_t)i*4*C+j];
      #pragma unroll
      for(int t=0;t<TC;t++) acc[t]+=w*so[t*C+i];
    }
    #pragma unroll
    for(int t=0;t<TC;t++) shid[t*4*C+j]=geluf(acc[t]);
  }
  __syncthreads();

  {
    int o=tid&63, part=tid>>6;
    float acc[TC];
    #pragma unroll
    for(int t=0;t<TC;t++) acc[t]=(part==0)?b2[o]:0.f;
    for(int jj=0;jj<64;jj++){
      int j=part*64+jj;
      float w=W2[(size_t)j*C+o];
      #pragma unroll
      for(int t=0;t<TC;t++) acc[t]+=w*shid[t*4*C+j];
    }
    if(part==1){
      #pragma unroll
      for(int t=0;t<TC;t++) sq[t*C+o]=acc[t];
    }else if(part==2){
      #pragma unroll
      for(int t=0;t<TC;t++) sk[t*C+o]=acc[t];
    }else if(part==3){
      #pragma unroll
      for(int t=0;t<TC;t++) sv[t*C+o]=acc[t];
    }
    __syncthreads();
    if(part==0){
      #pragma unroll
      for(int t=0;t<TC;t++){
        float fin=acc[t]+sq[t*C+o]+sk[t*C+o]+sv[t*C+o]+sxa[t*C+o];
        shid[t*C+o]=fin;
      }
    }
  }
  __syncthreads();

  if(tid<128){
    int c=tid&63, m=tid>>6;
    const float* base=m?gw:fw;
    float acc[TN];
    #pragma unroll
    for(int tt=0;tt<TN;tt++) acc[tt]=0.f;
    for(int i=0;i<C;i++){
      float w0=base[i*C+c];
      float w1=base[C*C+i*C+c];
      #pragma unroll
      for(int tt=0;tt<TN;tt++) acc[tt]+=w0*shid[tt*C+i]+w1*shid[(tt+D)*C+i];
    }
    float bi=m?gb[c]:fb[c];
    if(m==0){
      #pragma unroll
      for(int tt=0;tt<TN;tt++) sq[tt*C+c]=tanhf(acc[tt]+bi);
    }else{
      #pragma unroll
      for(int tt=0;tt<TN;tt++) sk[tt*C+c]=sigmf(acc[tt]+bi);
    }
  }
  __syncthreads();

  if(tid<C) so[tid]=sq[(TN-1)*C+tid]*sk[(TN-1)*C+tid];
  __syncthreads();

  {
    float a=skb[tid];
    for(int i=0;i<C;i++) a+=so[i]*skw[i*SKC+tid];
    skipacc[((size_t)b*SKC+tid)*N+n]+=a;
  }

  size_t obase=(size_t)bn*C*TN;
  for(int idx=tid; idx<C*TN; idx+=256){
    int c=idx/TN, tt=idx%TN;
    float v=sq[tt*C+c]*sk[tt*C+c];
    unsigned short h=f2us(v);
    hThi[obase+idx]=h;
    hTlo[obase+idx]=f2us(v-us2f(h));
  }
}

// ---- MFMA spatial GEMM: Y[w][col] = sum_v M[w][v] * X[v][col] ----
// M as bf16 split (Ah,Al), row-major [w][v] padded stride NP (rows also padded/zeroed).
// X as bf16 split [b][N][M]. Y written as bf16 split [b][N][M].
// Split product: M*X ~= AhXh + AhXl + AlXh  (rel err ~2^-17).
// Tile 64x64, BK=32 (one MFMA-K per stage). 256 thr = 4 waves in 2x2 quadrants.
__global__ __launch_bounds__(256) void k_spatmm(
    const unsigned short* __restrict__ Ah, const unsigned short* __restrict__ Al,
    long long aStride,
    const unsigned short* __restrict__ Xh, const unsigned short* __restrict__ Xl,
    unsigned short* __restrict__ Yh, unsigned short* __restrict__ Yl, int M){
  typedef __attribute__((ext_vector_type(8))) short bf16x8;
  typedef __attribute__((ext_vector_type(4))) float f32x4;
  __shared__ unsigned short sAh[64*40];
  __shared__ unsigned short sAl[64*40];
  __shared__ unsigned short sXh[64*40];
  __shared__ unsigned short sXl[64*40];
  int b=blockIdx.z;
  const unsigned short* Abh=Ah+(size_t)b*aStride;
  const unsigned short* Abl=Al+(size_t)b*aStride;
  const unsigned short* Xbh=Xh+(size_t)b*N*M;
  const unsigned short* Xbl=Xl+(size_t)b*N*M;
  int tid=threadIdx.x;
  int w0=blockIdx.x*64, c0=blockIdx.y*64;
  int lane=tid&63, wid=tid>>6;
  int wr=wid>>1, wc=wid&1;
  int lr=lane&15, lg=lane>>4;
  f32x4 acc[2][2];
  #pragma unroll
  for(int j=0;j<2;j++){
    #pragma unroll
    for(int i=0;i<2;i++){ acc[j][i][0]=0.f; acc[j][i][1]=0.f; acc[j][i][2]=0.f; acc[j][i][3]=0.f; }
  }
  const int ar=tid>>2, akb=(tid&3)*8;        // A staging: row, k-base
  const int xk=tid>>3, xcb=(tid&7)*8;        // X staging: k, col-base
  const int xkx=xk ^ (8*((xcb>>3)&3));       // swizzled k-slot (uniform over the 8 cols)
  for(int k0=0;k0<N;k0+=32){
    { // A staging: clean uint4 load + b128 LDS store (pad rows/cols are zeroed)
      uint4 qh=*(const uint4*)&Abh[(size_t)(w0+ar)*NP + k0+akb];
      uint4 ql=*(const uint4*)&Abl[(size_t)(w0+ar)*NP + k0+akb];
      *(uint4*)&sAh[ar*40+akb]=qh;
      *(uint4*)&sAl[ar*40+akb]=ql;
    }
    { // X staging: uint4 load, transposed scatter with k-slot XOR swizzle
      uint4 qh={0,0,0,0}, ql={0,0,0,0};
      if(k0+xk<N){
        qh=*(const uint4*)&Xbh[(size_t)(k0+xk)*M + c0+xcb];
        ql=*(const uint4*)&Xbl[(size_t)(k0+xk)*M + c0+xcb];
      }
      unsigned short uh[8], ul[8];
      uh[0]=(unsigned short)(qh.x&0xffff); uh[1]=(unsigned short)(qh.x>>16);
      uh[2]=(unsigned short)(qh.y&0xffff); uh[3]=(unsigned short)(qh.y>>16);
      uh[4]=(unsigned short)(qh.z&0xffff); uh[5]=(unsigned short)(qh.z>>16);
      uh[6]=(unsigned short)(qh.w&0xffff); uh[7]=(unsigned short)(qh.w>>16);
      ul[0]=(unsigned short)(ql.x&0xffff); ul[1]=(unsigned short)(ql.x>>16);
      ul[2]=(unsigned short)(ql.y&0xffff); ul[3]=(unsigned short)(ql.y>>16);
      ul[4]=(unsigned short)(ql.z&0xffff); ul[5]=(unsigned short)(ql.z>>16);
      ul[6]=(unsigned short)(ql.w&0xffff); ul[7]=(unsigned short)(ql.w>>16);
      #pragma unroll
      for(int j=0;j<8;j++){
        sXh[(xcb+j)*40+xkx]=uh[j];
        sXl[(xcb+j)*40+xkx]=ul[j];
      }
    }
    __syncthreads();
    bf16x8 a_h[2], a_l[2], x_h[2], x_l[2];
    #pragma unroll
    for(int j=0;j<2;j++){
      int r=32*wr+16*j+lr;
      a_h[j]=*(const bf16x8*)&sAh[r*40+8*lg];
      a_l[j]=*(const bf16x8*)&sAl[r*40+8*lg];
    }
    #pragma unroll
    for(int i=0;i<2;i++){
      int cc=32*wc+16*i+lr;
      int g=lg ^ ((cc>>3)&3);
      x_h[i]=*(const bf16x8*)&sXh[cc*40+8*g];
      x_l[i]=*(const bf16x8*)&sXl[cc*40+8*g];
    }
    #pragma unroll
    for(int j=0;j<2;j++){
      #pragma unroll
      for(int i=0;i<2;i++){
        acc[j][i]=__builtin_amdgcn_mfma_f32_16x16x32_bf16(a_h[j],x_h[i],acc[j][i],0,0,0);
        acc[j][i]=__builtin_amdgcn_mfma_f32_16x16x32_bf16(a_h[j],x_l[i],acc[j][i],0,0,0);
        acc[j][i]=__builtin_amdgcn_mfma_f32_16x16x32_bf16(a_l[j],x_h[i],acc[j][i],0,0,0);
      }
    }
    __syncthreads();
  }
  // epilogue: C/D layout col=lane&15, row=(lane>>4)*4+reg [m89]
  #pragma unroll
  for(int j=0;j<2;j++){
    int rbase=w0+32*wr+16*j+lg*4;
    #pragma unroll
    for(int i=0;i<2;i++){
      int col=c0+32*wc+16*i+lr;
      #pragma unroll
      for(int r=0;r<4;r++){
        int row=rbase+r;
        if(row<N){
          float v=acc[j][i][r];
          unsigned short h=f2us(v);
          unsigned short lo=f2us(v-us2f(h));
          size_t o=((size_t)b*N+row)*M+col;
          Yh[o]=h; Yl[o]=lo;
        }
      }
    }
  }
}

// fused GCN projection over NS = FIRST + 2 slices (hT?, P, Q), bf16 hi/lo inputs.
template<int TN, int FIRST>
__global__ __launch_bounds__(256) void k_gcnprojB(
    const unsigned short* __restrict__ S0h, const unsigned short* __restrict__ S0l,
    const unsigned short* __restrict__ Ph, const unsigned short* __restrict__ Pl,
    const unsigned short* __restrict__ Qh, const unsigned short* __restrict__ Ql,
    const float* __restrict__ Wg, const float* __restrict__ gb,
    const float* __restrict__ res, float* __restrict__ acc, int Tc){
  constexpr int NS=FIRST+2;
  constexpr int SL=C*TN;
  constexpr int LDSF=((NS*C>256)?NS*C:256)*TN;
  int bn=blockIdx.x; int tid=threadIdx.x;
  int n=bn%N, b=bn/N;
  __shared__ float sx[LDSF];
  size_t base=(size_t)bn*SL;
  if(FIRST){
    for(int i=tid;i<SL;i+=256) sx[i]=us2f(S0h[base+i])+us2f(S0l[base+i]);
  }
  for(int i=tid;i<SL;i+=256){
    sx[(FIRST+0)*SL+i]=us2f(Ph[base+i])+us2f(Pl[base+i]);
    sx[(FIRST+1)*SL+i]=us2f(Qh[base+i])+us2f(Ql[base+i]);
  }
  __syncthreads();
  int o=tid&63, part=tid>>6;
  float a[TN];
  #pragma unroll
  for(int tt=0;tt<TN;tt++) a[tt]=0.f;
  for(int j=0;j<NS;j++){
    const float* Wj=Wg+(size_t)j*C*C;
    const float* xj=&sx[j*SL];
    for(int ii=0;ii<16;ii++){
      int i=part*16+ii;
      float w=Wj[i*C+o];
      #pragma unroll
      for(int tt=0;tt<TN;tt++) a[tt]+=w*xj[i*TN+tt];
    }
  }
  __syncthreads();
  float* red=sx;
  #pragma unroll
  for(int tt=0;tt<TN;tt++) red[(part*64+o)*TN+tt]=a[tt];
  __syncthreads();
  if(part==0){
    size_t ob=(((size_t)b*C+o)*N+n)*TN;
    float v[TN];
    #pragma unroll
    for(int tt=0;tt<TN;tt++)
      v[tt]=red[o*TN+tt]+red[(64+o)*TN+tt]+red[(128+o)*TN+tt]+red[(192+o)*TN+tt];
    if(FIRST){
      float g=gb[o];
      size_t rb=(((size_t)b*C+o)*N+n)*Tc+(Tc-TN);
      #pragma unroll
      for(int tt=0;tt<TN;tt++) acc[ob+tt]=v[tt]+g+res[rb+tt];
    }else{
      #pragma unroll
      for(int tt=0;tt<TN;tt++) acc[ob+tt]+=v[tt];
    }
  }
}

__global__ void k_bnstats(const float* __restrict__ h, float* __restrict__ st, int tn){
  int c=blockIdx.x, tid=threadIdx.x;
  __shared__ float rs[256], rq[256];
  const int Mi=N*tn;
  const int M=B*Mi;
  float s=0.f,q=0.f;
  for(int idx=tid; idx<M; idx+=256){
    int b=idx/Mi; int inner=idx%Mi;
    float v=h[(size_t)b*C*Mi + (size_t)c*Mi + inner];
    s+=v; q+=v*v;
  }
  rs[tid]=s; rq[tid]=q; __syncthreads();
  for(int k=128;k>0;k>>=1){ if(tid<k){ rs[tid]+=rs[tid+k]; rq[tid]+=rq[tid+k]; } __syncthreads(); }
  if(tid==0){
    float mu=rs[0]/M; float var=rq[0]/M-mu*mu;
    st[c]=mu; st[C+c]=rsqrtf(var+1e-5f);
  }
}

__global__ void k_bnapply(float* __restrict__ h, const float* __restrict__ st,
                          const float* __restrict__ g, const float* __restrict__ bb, int tn){
  int idx=blockIdx.x*256+threadIdx.x;
  if(idx>=B*C*N*tn) return;
  int c=(idx/(N*tn))%C;
  float v=h[idx];
  h[idx]=(v-st[c])*st[C+c]*g[c]+bb[c];
}

__global__ void k_head(const float* __restrict__ skipacc, const float* __restrict__ W1,
  const float* __restrict__ b1, const float* __restrict__ W2, const float* __restrict__ b2,
  float* __restrict__ out){
  int gid=blockIdx.x; int tid=threadIdx.x;  // 512 threads
  int n=gid%N; int b=gid/N;
  __shared__ float s[SKC];
  __shared__ float hid[512];
  if(tid<SKC){
    float v=skipacc[((size_t)b*SKC+tid)*N+n];
    s[tid]=fmaxf(v,0.f);
  }
  __syncthreads();
  {
    float a=b1[tid];
    for(int i=0;i<SKC;i++) a+=s[i]*W1[(size_t)i*512+tid];
    hid[tid]=fmaxf(a,0.f);
  }
  __syncthreads();
  if(tid<T){
    float a=b2[tid];
    for(int j=0;j<512;j++) a+=hid[j]*W2[(size_t)j*T+tid];
    out[((size_t)b*T+tid)*N+n]=a;
  }
}

// ---------------- host-side layer driver ----------------
struct Ctx {
  const float *Wq,*bq,*Wk,*bk,*Wv,*bv,*W1,*b1,*W2,*b2;
  const float *filt_w,*filt_b,*gate_w,*gate_b,*skip_w,*skip_b,*gcn_w,*gcn_b,*bn_g,*bn_b;
  const unsigned short* matH[4];
  const unsigned short* matL[4];
  long long matStride[4];
  float *pH,*pAlt,*skipacc,*bnst;
  unsigned short *hThi,*hTlo,*Phi,*Plo,*Qhi,*Qlo;
  hipStream_t stream;
};

template<int TC, int D>
void run_layer(Ctx& c, int l, bool last){
  constexpr int TN=TC-D;
  const size_t CC=(size_t)C*C;
  k_attconv<TC,D><<<B*N,256,0,c.stream>>>(c.pH,
    c.Wq+(size_t)l*CC, c.bq+(size_t)l*C,
    c.Wk+(size_t)l*CC, c.bk+(size_t)l*C,
    c.Wv+(size_t)l*CC, c.bv+(size_t)l*C,
    c.W1+(size_t)l*C*4*C, c.b1+(size_t)l*4*C,
    c.W2+(size_t)l*4*C*C, c.b2+(size_t)l*C,
    c.filt_w+(size_t)l*2*CC, c.filt_b+(size_t)l*C,
    c.gate_w+(size_t)l*2*CC, c.gate_b+(size_t)l*C,
    c.skip_w+(size_t)l*C*SKC, c.skip_b+(size_t)l*SKC,
    c.hThi, c.hTlo, c.skipacc);
  if(!last){
    int M=C*TN, nMB=M/64;
    const float* Wl=c.gcn_w+(size_t)l*9*CC;
    dim3 sg(DIVUP(N,64), nMB, B);
    for(int s=0;s<4;s++){
      k_spatmm<<<sg,256,0,c.stream>>>(c.matH[s],c.matL[s],c.matStride[s],
          c.hThi,c.hTlo, c.Phi,c.Plo, M);
      k_spatmm<<<sg,256,0,c.stream>>>(c.matH[s],c.matL[s],c.matStride[s],
          c.Phi,c.Plo, c.Qhi,c.Qlo, M);
      if(s==0){
        k_gcnprojB<TN,1><<<B*N,256,0,c.stream>>>(c.hThi,c.hTlo,
            c.Phi,c.Plo,c.Qhi,c.Qlo,
            Wl, c.gcn_b+(size_t)l*C, c.pH, c.pAlt, TC);
      }else{
        k_gcnprojB<TN,0><<<B*N,256,0,c.stream>>>(nullptr,nullptr,
            c.Phi,c.Plo,c.Qhi,c.Qlo,
            Wl+(size_t)(1+2*s)*CC, nullptr, nullptr, c.pAlt, TC);
      }
    }
    k_bnstats<<<C,256,0,c.stream>>>(c.pAlt, c.bnst, TN);
    k_bnapply<<<DIVUP(B*C*N*TN,256),256,0,c.stream>>>(c.pAlt, c.bnst,
      c.bn_g+(size_t)l*C, c.bn_b+(size_t)l*C, TN);
    float* tmp=c.pH; c.pH=c.pAlt; c.pAlt=tmp;
  }
}

} // namespace

extern "C" void kernel_launch(void* const* d_in, const int* in_sizes, int n_in,
                              void* d_out, int out_size, void* d_ws, size_t ws_size,
                              hipStream_t stream){
  (void)in_sizes; (void)n_in;
  const float* x      =(const float*)d_in[0];
  const float* sup0   =(const float*)d_in[1];
  const float* sup1   =(const float*)d_in[2];
  const float* TiD    =(const float*)d_in[3];
  const float* DiW    =(const float*)d_in[4];
  const float* E1     =(const float*)d_in[5];
  const float* E2     =(const float*)d_in[6];
  const float* E3     =(const float*)d_in[7];
  const float* Wx     =(const float*)d_in[8];
  const float* Wd     =(const float*)d_in[9];
  const float* Wxabs  =(const float*)d_in[10];
  const float* start_w=(const float*)d_in[11];
  const float* start_b=(const float*)d_in[12];

  Ctx c;
  c.Wq=(const float*)d_in[13]; c.bq=(const float*)d_in[14];
  c.Wk=(const float*)d_in[15]; c.bk=(const float*)d_in[16];
  c.Wv=(const float*)d_in[17]; c.bv=(const float*)d_in[18];
  c.W1=(const float*)d_in[19]; c.b1=(const float*)d_in[20];
  c.W2=(const float*)d_in[21]; c.b2=(const float*)d_in[22];
  c.filt_w=(const float*)d_in[23]; c.filt_b=(const float*)d_in[24];
  c.gate_w=(const float*)d_in[25]; c.gate_b=(const float*)d_in[26];
  c.skip_w=(const float*)d_in[27]; c.skip_b=(const float*)d_in[28];
  c.gcn_w =(const float*)d_in[29]; c.gcn_b =(const float*)d_in[30];
  c.bn_g  =(const float*)d_in[31]; c.bn_b  =(const float*)d_in[32];
  const float* end1_w =(const float*)d_in[33];
  const float* end1_b =(const float*)d_in[34];
  const float* end2_w =(const float*)d_in[35];
  const float* end2_b =(const float*)d_in[36];
  c.stream=stream;

  // workspace carve (16B-aligned)
  size_t off=0;
  auto allocF=[&](size_t nf)->float*{
    nf=(nf+3)&~(size_t)3;
    float* p=(float*)((char*)d_ws+off);
    off += nf*sizeof(float);
    return p;
  };
  auto allocU=[&](size_t nu)->unsigned short*{
    nu=(nu+7)&~(size_t)7;
    unsigned short* p=(unsigned short*)((char*)d_ws+off);
    off += nu*sizeof(unsigned short);
    return p;
  };
  const size_t HMAX =(size_t)B*C*N*T13;
  const size_t XSZ  =(size_t)B*C*N*12;      // max M per b is C*12
  const size_t SUPP =(size_t)NP*NP;
  const size_t ADSZ =(size_t)B*NP*NP;

  float* xf     = allocF((size_t)B*F7*N);
  float* gx1    = allocF((size_t)B*N*E);
  float* gdew   = allocF((size_t)B*N*E);
  float* gst    = allocF(16);
  c.bnst        = allocF(2*C);
  float* adp    = allocF((size_t)B*N*N);
  c.pH          = allocF(HMAX);
  c.pAlt        = allocF(HMAX);
  c.skipacc     = allocF((size_t)B*SKC*N);
  // bf16 support matrices (contiguous region, pre-zeroed for padding)
  unsigned short* matRegion=(unsigned short*)((char*)d_ws+off);
  unsigned short* s0h = allocU(SUPP);
  unsigned short* s0l = allocU(SUPP);
  unsigned short* s1h = allocU(SUPP);
  unsigned short* s1l = allocU(SUPP);
  unsigned short* aph = allocU(SUPP);
  unsigned short* apl = allocU(SUPP);
  unsigned short* adh = allocU(ADSZ);
  unsigned short* adl = allocU(ADSZ);
  long long matRegionN = (long long)(( (unsigned short*)((char*)d_ws+off) ) - matRegion);
  c.hThi = allocU(XSZ);  c.hTlo = allocU(XSZ);
  c.Phi  = allocU(XSZ);  c.Plo  = allocU(XSZ);
  c.Qhi  = allocU(XSZ);  c.Qlo  = allocU(XSZ);
  if(off > ws_size){
    k_zero<<<DIVUP(out_size,256),256,0,stream>>>((float*)d_out, out_size);
    return;
  }
  c.matH[0]=s0h; c.matL[0]=s0l; c.matStride[0]=0;
  c.matH[1]=s1h; c.matL[1]=s1l; c.matStride[1]=0;
  c.matH[2]=aph; c.matL[2]=apl; c.matStride[2]=0;
  c.matH[3]=adh; c.matL[3]=adl; c.matStride[3]=(long long)NP*NP;

  // ---- graph generation + support conversion ----
  k_zeroUS<<<(int)DIVUP(matRegionN,256),256,0,stream>>>(matRegion, matRegionN);
  k_dft <<<DIVUP(B*F7*N,256),256,0,stream>>>(x, xf);
  k_l2f <<<DIVUP(B*N,256),256,0,stream>>>(xf);
  k_l2n <<<B*F7,256,0,stream>>>(xf);
  k_x1  <<<DIVUP(B*N,256),256,0,stream>>>(x, xf, E3, TiD, DiW, Wx, Wd, gx1);
  k_lnstats<<<B,256,0,stream>>>(gx1, gst);
  k_dew <<<DIVUP(B*N,256),256,0,stream>>>(gx1, gst, Wxabs, gdew);
  k_adp <<<DIVUP(B*N*N,256),256,0,stream>>>(gdew, gx1, adp);
  k_topk<<<B*N,256,0,stream>>>(adp, adh, adl);
  k_adap<<<N,256,0,stream>>>(E1, E2, aph, apl);
  k_cvtT<<<DIVUP(N*N,256),256,0,stream>>>(sup0, s0h, s0l);
  k_cvtT<<<DIVUP(N*N,256),256,0,stream>>>(sup1, s1h, s1l);

  // ---- trunk ----
  k_zero<<<DIVUP(B*SKC*N,256),256,0,stream>>>(c.skipacc, B*SKC*N);
  k_start<<<DIVUP(B*C*N*T13,256),256,0,stream>>>(x, start_w, start_b, c.pH);

  run_layer<13,1>(c,0,false);
  run_layer<12,2>(c,1,false);
  run_layer<10,1>(c,2,false);
  run_layer< 9,2>(c,3,false);
  run_layer< 7,1>(c,4,false);
  run_layer< 6,2>(c,5,false);
  run_layer< 4,1>(c,6,false);
  run_layer< 3,2>(c,7,true);

  k_head<<<B*N,512,0,stream>>>(c.skipacc, end1_w, end1_b, end2_w, end2_b, (float*)d_out);
}